// Round 2
// baseline (436.647 us; speedup 1.0000x reference)
//
#include <hip/hip_runtime.h>
#include <hip/hip_bf16.h>
#include <math.h>

#define NN 4096
#define EE 131072
#define EP (EE + NN)     // 135168 edges incl. self loops
#define C1 512
#define H1 8
#define C2 256
#define NWORDS 128       // 4096 bits / 32

__device__ __forceinline__ float wredMaxf(float v){
#pragma unroll
  for(int o=32;o;o>>=1) v = fmaxf(v, __shfl_xor(v,o));
  return v;
}
__device__ __forceinline__ float wredSumf(float v){
#pragma unroll
  for(int o=32;o;o>>=1) v += __shfl_xor(v,o);
  return v;
}
__device__ __forceinline__ int wredSumi(int v){
#pragma unroll
  for(int o=32;o;o>>=1) v += __shfl_xor(v,o);
  return v;
}

// ---- edge dtype detection: int64 => high 32-bit words are all zero ----
__global__ __launch_bounds__(256) void k_detect(const int* __restrict__ ei32, int* __restrict__ mode){
  __shared__ int any;
  if(threadIdx.x==0) any = 0;
  __syncthreads();
  int nz = 0;
  for(int i=threadIdx.x;i<2048;i+=256) nz |= (ei32[2*i+1] != 0);
  if(nz) atomicOr(&any, 1);
  __syncthreads();
  if(threadIdx.x==0) *mode = any;   // 1 => int32, 0 => int64
}

__device__ __forceinline__ void edge_sd(const int* ei32, int mode, int e, int& s, int& d){
  if(e < EE){
    if(mode==0){ s = ei32[2*e]; d = ei32[2*(EE+e)]; }
    else       { s = ei32[e];   d = ei32[EE+e]; }
  } else { s = e - EE; d = s; }
}

__global__ __launch_bounds__(256) void k_build(const int* __restrict__ ei32, const int* __restrict__ mode,
    unsigned* __restrict__ rowbits, unsigned* __restrict__ colbits, unsigned* __restrict__ cnt){
  int e = blockIdx.x*256 + threadIdx.x;
  if(e >= EP) return;
  int m = *mode, s, d;
  edge_sd(ei32, m, e, s, d);
  atomicOr(&rowbits[s*NWORDS + (d>>5)], 1u<<(d&31));
  atomicOr(&colbits[d*NWORDS + (s>>5)], 1u<<(s&31));
  atomicAdd(&cnt[d], 1u);
}

__global__ __launch_bounds__(256) void k_scan(const unsigned* __restrict__ cnt, unsigned* __restrict__ rowptr){
  __shared__ unsigned part[256];
  int t = threadIdx.x;
  unsigned loc[16]; unsigned s = 0;
#pragma unroll
  for(int i=0;i<16;i++){ loc[i]=cnt[t*16+i]; s+=loc[i]; }
  part[t]=s; __syncthreads();
  for(int off=1;off<256;off<<=1){
    unsigned v = (t>=off)? part[t-off] : 0u;
    __syncthreads();
    part[t]+=v;
    __syncthreads();
  }
  unsigned run = (t==0)? 0u : part[t-1];
#pragma unroll
  for(int i=0;i<16;i++){ rowptr[t*16+i]=run; run+=loc[i]; }
  if(t==255) rowptr[NN]=run;
}

__global__ __launch_bounds__(256) void k_fill(const int* __restrict__ ei32, const int* __restrict__ mode,
    const unsigned* __restrict__ rowptr, unsigned* __restrict__ fill,
    unsigned* __restrict__ csr_src, unsigned* __restrict__ csr_eid){
  int e = blockIdx.x*256 + threadIdx.x;
  if(e >= EP) return;
  int m = *mode, s, d;
  edge_sd(ei32, m, e, s, d);
  unsigned pos = rowptr[d] + atomicAdd(&fill[d], 1u);
  csr_src[pos]=(unsigned)s; csr_eid[pos]=(unsigned)e;
}

// v1 = A @ 1 (out-degree incl. self loop)
__global__ __launch_bounds__(256) void k_deg(const unsigned* __restrict__ rowbits, float* __restrict__ v1){
  int node = blockIdx.x*4 + (threadIdx.x>>6);
  int lane = threadIdx.x & 63;
  unsigned w0 = rowbits[node*NWORDS + 2*lane];
  unsigned w1 = rowbits[node*NWORDS + 2*lane + 1];
  int c = __popc(w0) + __popc(w1);
  c = wredSumi(c);
  if(lane==0) v1[node] = (float)c;
}

// vout = A @ vin
__global__ __launch_bounds__(256) void k_mv(const unsigned* __restrict__ rowbits,
    const float* __restrict__ vin, float* __restrict__ vout){
  int node = blockIdx.x*4 + (threadIdx.x>>6);
  int lane = threadIdx.x & 63;
  float sum = 0.f;
  unsigned w = rowbits[node*NWORDS + 2*lane]; int b0 = lane*64;
  while(w){ int b=__ffs(w)-1; sum += vin[b0+b]; w &= w-1; }
  w = rowbits[node*NWORDS + 2*lane + 1]; b0 = lane*64 + 32;
  while(w){ int b=__ffs(w)-1; sum += vin[b0+b]; w &= w-1; }
  sum = wredSumf(sum);
  if(lane==0) vout[node] = sum;
}

// per-dst: g[k] = A^2[k,d]; per in-edge (s,d): A^3[s,d] = sum_{k in out(s)} g[k]; mw = A3/max(rowsum3[s],1)
__global__ __launch_bounds__(64) void k_motif(const unsigned* __restrict__ rowbits, const unsigned* __restrict__ colbits,
    const unsigned* __restrict__ rowptr, const unsigned* __restrict__ csr_src, const unsigned* __restrict__ csr_eid,
    const float* __restrict__ v3, float* __restrict__ mw){
  int d = blockIdx.x;
  int lane = threadIdx.x;
  __shared__ unsigned g32[1024];              // 4096 byte counters
  unsigned char* g = (unsigned char*)g32;
  __shared__ unsigned short nbr[4096];
  __shared__ int cntL;
  for(int i=lane;i<1024;i+=64) g32[i]=0u;
  if(lane==0) cntL=0;
  __syncthreads();
  // in-neighbor list of d (unique, from colbits)
  {
    unsigned w = colbits[d*NWORDS + 2*lane]; int b0 = lane*64;
    while(w){ int b=__ffs(w)-1; int pos=atomicAdd(&cntL,1); nbr[pos]=(unsigned short)(b0+b); w&=w-1; }
    w = colbits[d*NWORDS + 2*lane + 1]; b0 = lane*64 + 32;
    while(w){ int b=__ffs(w)-1; int pos=atomicAdd(&cntL,1); nbr[pos]=(unsigned short)(b0+b); w&=w-1; }
  }
  __syncthreads();
  int m = cntL;
  for(int t=0;t<m;t++){
    int l = nbr[t];
    unsigned w = colbits[l*NWORDS + 2*lane]; int b0 = lane*64;       // lane owns bytes [64*lane, 64*lane+64)
    while(w){ int b=__ffs(w)-1; g[b0+b]++; w&=w-1; }
    w = colbits[l*NWORDS + 2*lane + 1]; b0 = lane*64 + 32;
    while(w){ int b=__ffs(w)-1; g[b0+b]++; w&=w-1; }
  }
  __syncthreads();
  unsigned base = rowptr[d], deg = rowptr[d+1]-base;
  for(unsigned i=0;i<deg;i++){
    int s = csr_src[base+i];
    int sum = 0;
    unsigned w = rowbits[s*NWORDS + 2*lane]; int b0 = lane*64;
    while(w){ int b=__ffs(w)-1; sum += (int)g[b0+b]; w&=w-1; }
    w = rowbits[s*NWORDS + 2*lane + 1]; b0 = lane*64 + 32;
    while(w){ int b=__ffs(w)-1; sum += (int)g[b0+b]; w&=w-1; }
    sum = wredSumi(sum);
    if(lane==0){
      float A3 = (float)sum;
      mw[csr_eid[base+i]] = A3 / fmaxf(v3[s], 1.0f);
    }
  }
}

// ---- f32 tiled GEMM: C[M,N] = A[M,K] @ B[K,N]; M,N mult of 64, K mult of 16 ----
#define GBM 64
#define GBN 64
#define GBK 16
__global__ __launch_bounds__(256) void k_gemm(const float* __restrict__ A, const float* __restrict__ B,
    float* __restrict__ C, int M, int N, int K){
  __shared__ float As[GBK][68];
  __shared__ float Bs[GBK][68];
  int bm = blockIdx.y*GBM, bn = blockIdx.x*GBN;
  int t = threadIdx.x;
  int tm = t>>4, tn = t&15;
  float acc[4][4];
#pragma unroll
  for(int i=0;i<4;i++)
#pragma unroll
    for(int j=0;j<4;j++) acc[i][j]=0.f;
  for(int k0=0;k0<K;k0+=GBK){
    {
      int mm = t>>2, kq = t&3;
      const float4 av = *(const float4*)&A[(size_t)(bm+mm)*K + k0 + kq*4];
      As[kq*4+0][mm]=av.x; As[kq*4+1][mm]=av.y; As[kq*4+2][mm]=av.z; As[kq*4+3][mm]=av.w;
      int kb = t>>4, nq = t&15;
      const float4 bv = *(const float4*)&B[(size_t)(k0+kb)*N + bn + nq*4];
      *(float4*)&Bs[kb][nq*4] = bv;
    }
    __syncthreads();
#pragma unroll
    for(int k=0;k<GBK;k++){
      const float4 a = *(const float4*)&As[k][tm*4];
      const float4 b = *(const float4*)&Bs[k][tn*4];
      float aa[4]={a.x,a.y,a.z,a.w}, bb[4]={b.x,b.y,b.z,b.w};
#pragma unroll
      for(int i=0;i<4;i++)
#pragma unroll
        for(int j=0;j<4;j++) acc[i][j] += aa[i]*bb[j];
    }
    __syncthreads();
  }
#pragma unroll
  for(int i=0;i<4;i++){
    float4 o = {acc[i][0],acc[i][1],acc[i][2],acc[i][3]};
    *(float4*)&C[(size_t)(bm+tm*4+i)*N + bn + tn*4] = o;
  }
}

// per-node attention logit dots, layer 1 (8 heads x 64 ch)
__global__ __launch_bounds__(512) void k_attn1(const float* __restrict__ hpre, const float* __restrict__ as1,
    const float* __restrict__ ad1, float* __restrict__ asrc, float* __restrict__ adst){
  int n = blockIdx.x; int t = threadIdx.x; int lane = t&63; int h = t>>6;
  float v = hpre[n*C1 + t];
  float p1 = v*as1[t], p2 = v*ad1[t];
  p1 = wredSumf(p1); p2 = wredSumf(p2);
  if(lane==0){ asrc[n*H1+h]=p1; adst[n*H1+h]=p2; }
}

// layer-1 dual segment-softmax + aggregation + bias + ELU
__global__ __launch_bounds__(128) void k_layer1(const unsigned* __restrict__ rowptr, const unsigned* __restrict__ csr_src,
    const unsigned* __restrict__ csr_eid, const float* __restrict__ mw, const float* __restrict__ asrc,
    const float* __restrict__ adst, const float* __restrict__ hpre, const float* __restrict__ b1,
    float* __restrict__ h1){
  int n = blockIdx.x;
  int tid = threadIdx.x, lane = tid&63, wv = tid>>6;
  unsigned base = rowptr[n], deg = rowptr[n+1]-base;
  __shared__ float adsts[8];
  __shared__ float r1[2][8], r2[2][8];
  __shared__ float sM1[8], sM2[8], sS1[8], sS2[8];
  if(tid<8) adsts[tid] = adst[n*H1+tid];
  __syncthreads();
  float ad[8];
#pragma unroll
  for(int h=0;h<8;h++) ad[h]=adsts[h];
  float m1[8], m2[8];
#pragma unroll
  for(int h=0;h<8;h++){ m1[h]=-3.0e38f; m2[h]=-3.0e38f; }
  for(unsigned i=tid;i<deg;i+=128){
    unsigned s = csr_src[base+i];
    float mwv = mw[csr_eid[base+i]];
    const float4 a0 = *(const float4*)&asrc[s*H1];
    const float4 a1 = *(const float4*)&asrc[s*H1+4];
    float as8[8]={a0.x,a0.y,a0.z,a0.w,a1.x,a1.y,a1.z,a1.w};
#pragma unroll
    for(int h=0;h<8;h++){
      float ev = as8[h]+ad[h];
      float el = ev>=0.f? ev : 0.2f*ev;
      float evm = ev*mwv;
      float em = evm>=0.f? evm : 0.2f*evm;
      m1[h]=fmaxf(m1[h],el); m2[h]=fmaxf(m2[h],em);
    }
  }
#pragma unroll
  for(int h=0;h<8;h++){ m1[h]=wredMaxf(m1[h]); m2[h]=wredMaxf(m2[h]); }
  if(lane==0){
#pragma unroll
    for(int h=0;h<8;h++){ r1[wv][h]=m1[h]; r2[wv][h]=m2[h]; }
  }
  __syncthreads();
  if(tid<8){ sM1[tid]=fmaxf(r1[0][tid],r1[1][tid]); sM2[tid]=fmaxf(r2[0][tid],r2[1][tid]); }
  __syncthreads();
  float s1[8], s2[8];
#pragma unroll
  for(int h=0;h<8;h++){ s1[h]=0.f; s2[h]=0.f; }
  for(unsigned i=tid;i<deg;i+=128){
    unsigned s = csr_src[base+i];
    float mwv = mw[csr_eid[base+i]];
    const float4 a0 = *(const float4*)&asrc[s*H1];
    const float4 a1 = *(const float4*)&asrc[s*H1+4];
    float as8[8]={a0.x,a0.y,a0.z,a0.w,a1.x,a1.y,a1.z,a1.w};
#pragma unroll
    for(int h=0;h<8;h++){
      float ev = as8[h]+ad[h];
      float el = ev>=0.f? ev : 0.2f*ev;
      float evm = ev*mwv;
      float em = evm>=0.f? evm : 0.2f*evm;
      s1[h] += expf(el - sM1[h]);
      s2[h] += expf(em - sM2[h]);
    }
  }
#pragma unroll
  for(int h=0;h<8;h++){ s1[h]=wredSumf(s1[h]); s2[h]=wredSumf(s2[h]); }
  __syncthreads();   // r1/r2 reads (for sM) done; safe to overwrite
  if(lane==0){
#pragma unroll
    for(int h=0;h<8;h++){ r1[wv][h]=s1[h]; r2[wv][h]=s2[h]; }
  }
  __syncthreads();
  if(tid<8){ sS1[tid]=r1[0][tid]+r1[1][tid]+1e-16f; sS2[tid]=r2[0][tid]+r2[1][tid]+1e-16f; }
  __syncthreads();
  // aggregation: thread owns 4 channels
  int c0 = tid*4; int h = tid>>4;
  float adh = adsts[h];
  float M1h = sM1[h], M2h = sM2[h], S1h = sS1[h], S2h = sS2[h];
  float4 acc = {0.f,0.f,0.f,0.f};
  for(unsigned i=0;i<deg;i++){
    unsigned s = csr_src[base+i];
    float mwv = mw[csr_eid[base+i]];
    float ev = asrc[s*H1+h] + adh;
    float el = ev>=0.f? ev : 0.2f*ev;
    float evm = ev*mwv;
    float em = evm>=0.f? evm : 0.2f*evm;
    float alpha = 0.5f*(expf(el-M1h)/S1h + expf(em-M2h)/S2h);
    const float4 hv = *(const float4*)&hpre[s*C1 + c0];
    acc.x += alpha*hv.x; acc.y += alpha*hv.y; acc.z += alpha*hv.z; acc.w += alpha*hv.w;
  }
  const float4 bv = *(const float4*)&b1[c0];
  float4 o;
  float vx = acc.x+bv.x; o.x = vx>0.f? vx : expm1f(vx);
  float vy = acc.y+bv.y; o.y = vy>0.f? vy : expm1f(vy);
  float vz = acc.z+bv.z; o.z = vz>0.f? vz : expm1f(vz);
  float vw = acc.w+bv.w; o.w = vw>0.f? vw : expm1f(vw);
  *(float4*)&h1[n*C1 + c0] = o;
}

// per-node attention logit dots, layer 2 (1 head x 256 ch)
__global__ __launch_bounds__(64) void k_attn2(const float* __restrict__ h2, const float* __restrict__ as2,
    const float* __restrict__ ad2, float* __restrict__ asrc, float* __restrict__ adst){
  int n = blockIdx.x; int lane = threadIdx.x;
  const float4 hv = *(const float4*)&h2[n*C2 + lane*4];
  const float4 av = *(const float4*)&as2[lane*4];
  const float4 dv = *(const float4*)&ad2[lane*4];
  float p1 = hv.x*av.x + hv.y*av.y + hv.z*av.z + hv.w*av.w;
  float p2 = hv.x*dv.x + hv.y*dv.y + hv.z*dv.z + hv.w*dv.w;
  p1 = wredSumf(p1); p2 = wredSumf(p2);
  if(lane==0){ asrc[n]=p1; adst[n]=p2; }
}

// layer-2: softmax + aggregation + residual + bias -> d_out
__global__ __launch_bounds__(64) void k_layer2(const unsigned* __restrict__ rowptr, const unsigned* __restrict__ csr_src,
    const unsigned* __restrict__ csr_eid, const float* __restrict__ mw, const float* __restrict__ asrc,
    const float* __restrict__ adst, const float* __restrict__ h2, const float* __restrict__ res,
    const float* __restrict__ b2, float* __restrict__ out){
  int n = blockIdx.x; int lane = threadIdx.x;
  unsigned base = rowptr[n], deg = rowptr[n+1]-base;
  float ad = adst[n];
  float m1=-3.0e38f, m2=-3.0e38f;
  for(unsigned i=lane;i<deg;i+=64){
    unsigned s = csr_src[base+i];
    float mwv = mw[csr_eid[base+i]];
    float ev = asrc[s] + ad;
    float el = ev>=0.f? ev : 0.2f*ev;
    float evm = ev*mwv;
    float em = evm>=0.f? evm : 0.2f*evm;
    m1=fmaxf(m1,el); m2=fmaxf(m2,em);
  }
  m1 = wredMaxf(m1); m2 = wredMaxf(m2);
  float s1=0.f, s2=0.f;
  for(unsigned i=lane;i<deg;i+=64){
    unsigned s = csr_src[base+i];
    float mwv = mw[csr_eid[base+i]];
    float ev = asrc[s] + ad;
    float el = ev>=0.f? ev : 0.2f*ev;
    float evm = ev*mwv;
    float em = evm>=0.f? evm : 0.2f*evm;
    s1 += expf(el-m1); s2 += expf(em-m2);
  }
  s1 = wredSumf(s1) + 1e-16f;
  s2 = wredSumf(s2) + 1e-16f;
  int c0 = lane*4;
  float4 acc = {0.f,0.f,0.f,0.f};
  for(unsigned i=0;i<deg;i++){
    unsigned s = csr_src[base+i];
    float mwv = mw[csr_eid[base+i]];
    float ev = asrc[s] + ad;
    float el = ev>=0.f? ev : 0.2f*ev;
    float evm = ev*mwv;
    float em = evm>=0.f? evm : 0.2f*evm;
    float alpha = 0.5f*(expf(el-m1)/s1 + expf(em-m2)/s2);
    const float4 hv = *(const float4*)&h2[s*C2 + c0];
    acc.x += alpha*hv.x; acc.y += alpha*hv.y; acc.z += alpha*hv.z; acc.w += alpha*hv.w;
  }
  const float4 rv = *(const float4*)&res[n*C2 + c0];
  const float4 bv = *(const float4*)&b2[c0];
  float4 o = {acc.x+rv.x+bv.x, acc.y+rv.y+bv.y, acc.z+rv.z+bv.z, acc.w+rv.w+bv.w};
  *(float4*)&out[n*C2 + c0] = o;
}

extern "C" void kernel_launch(void* const* d_in, const int* in_sizes, int n_in,
                              void* d_out, int out_size, void* d_ws, size_t ws_size,
                              hipStream_t stream) {
  const float* x    = (const float*)d_in[0];
  const int*   ei32 = (const int*)d_in[1];     // int64 vs int32 auto-detected
  const float* W1   = (const float*)d_in[2];
  const float* as1  = (const float*)d_in[3];
  const float* ad1  = (const float*)d_in[4];
  const float* b1   = (const float*)d_in[5];
  const float* W2   = (const float*)d_in[6];
  const float* as2  = (const float*)d_in[7];
  const float* ad2  = (const float*)d_in[8];
  const float* b2   = (const float*)d_in[9];
  const float* resW2= (const float*)d_in[10];
  float* out = (float*)d_out;

  char* p = (char*)d_ws;
  auto alloc = [&](size_t b){ void* r=(void*)p; p += (b + 255) & ~(size_t)255; return r; };
  unsigned* rowbits = (unsigned*)alloc((size_t)NN*NWORDS*4);   // 2MB
  unsigned* colbits = (unsigned*)alloc((size_t)NN*NWORDS*4);   // 2MB (contiguous with rowbits)
  unsigned* cnt     = (unsigned*)alloc(NN*4);
  unsigned* fill    = (unsigned*)alloc(NN*4);                  // contiguous with cnt
  unsigned* rowptr  = (unsigned*)alloc((NN+4)*4);
  float* v1 = (float*)alloc(NN*4);
  float* v2 = (float*)alloc(NN*4);
  float* v3 = (float*)alloc(NN*4);
  unsigned* csr_src = (unsigned*)alloc((size_t)EP*4);
  unsigned* csr_eid = (unsigned*)alloc((size_t)EP*4);
  float* mw   = (float*)alloc((size_t)EP*4);
  float* asrc1= (float*)alloc(NN*H1*4);
  float* adst1= (float*)alloc(NN*H1*4);
  float* hpre = (float*)alloc((size_t)NN*C1*4);   // 8MB; reused as h2+res after k_layer1
  float* h1   = (float*)alloc((size_t)NN*C1*4);   // 8MB
  float* asrc2= (float*)alloc(NN*4);
  float* adst2= (float*)alloc(NN*4);
  int* mode   = (int*)alloc(256);
  // hpre is dead after k_layer1 -> reuse its 8MB for h2 (4MB) + res (4MB)
  float* h2  = hpre;
  float* res = hpre + (size_t)NN*C2;

  hipMemsetAsync(rowbits, 0, (size_t)NN*NWORDS*4*2, stream);   // rowbits+colbits
  hipMemsetAsync(cnt, 0, (size_t)NN*4*2, stream);              // cnt+fill

  k_detect<<<1,256,0,stream>>>(ei32, mode);
  k_build<<<(EP+255)/256,256,0,stream>>>(ei32, mode, rowbits, colbits, cnt);
  k_scan<<<1,256,0,stream>>>(cnt, rowptr);
  k_fill<<<(EP+255)/256,256,0,stream>>>(ei32, mode, rowptr, fill, csr_src, csr_eid);
  k_deg<<<NN/4,256,0,stream>>>(rowbits, v1);
  k_mv<<<NN/4,256,0,stream>>>(rowbits, v1, v2);
  k_mv<<<NN/4,256,0,stream>>>(rowbits, v2, v3);
  k_motif<<<NN,64,0,stream>>>(rowbits, colbits, rowptr, csr_src, csr_eid, v3, mw);

  k_gemm<<<dim3(C1/GBN, NN/GBM),256,0,stream>>>(x, W1, hpre, NN, C1, C1);
  k_attn1<<<NN,512,0,stream>>>(hpre, as1, ad1, asrc1, adst1);
  k_layer1<<<NN,128,0,stream>>>(rowptr, csr_src, csr_eid, mw, asrc1, adst1, hpre, b1, h1);

  k_gemm<<<dim3(C2/GBN, NN/GBM),256,0,stream>>>(h1, W2, h2, NN, C2, C1);
  k_gemm<<<dim3(C2/GBN, NN/GBM),256,0,stream>>>(h1, resW2, res, NN, C2, C1);
  k_attn2<<<NN,64,0,stream>>>(h2, as2, ad2, asrc2, adst2);
  k_layer2<<<NN,64,0,stream>>>(rowptr, csr_src, csr_eid, mw, asrc2, adst2, h2, res, b2, out);
}

// Round 3
// 363.989 us; speedup vs baseline: 1.1996x; 1.1996x over previous
//
#include <hip/hip_runtime.h>
#include <hip/hip_bf16.h>
#include <math.h>

#define NN 4096
#define EE 131072
#define EP (EE + NN)     // 135168 edges incl. self loops
#define C1 512
#define H1 8
#define C2 256
#define NWORDS 128       // 4096 bits / 32

__device__ __forceinline__ float wredMaxf(float v){
#pragma unroll
  for(int o=32;o;o>>=1) v = fmaxf(v, __shfl_xor(v,o));
  return v;
}
__device__ __forceinline__ float wredSumf(float v){
#pragma unroll
  for(int o=32;o;o>>=1) v += __shfl_xor(v,o);
  return v;
}
__device__ __forceinline__ int wredSumi(int v){
#pragma unroll
  for(int o=32;o;o>>=1) v += __shfl_xor(v,o);
  return v;
}

// ---- edge dtype detection: int64 => high 32-bit words are all zero ----
__global__ __launch_bounds__(256) void k_detect(const int* __restrict__ ei32, int* __restrict__ mode){
  __shared__ int any;
  if(threadIdx.x==0) any = 0;
  __syncthreads();
  int nz = 0;
  for(int i=threadIdx.x;i<2048;i+=256) nz |= (ei32[2*i+1] != 0);
  if(nz) atomicOr(&any, 1);
  __syncthreads();
  if(threadIdx.x==0) *mode = any;   // 1 => int32, 0 => int64
}

__device__ __forceinline__ void edge_sd(const int* ei32, int mode, int e, int& s, int& d){
  if(e < EE){
    if(mode==0){ s = ei32[2*e]; d = ei32[2*(EE+e)]; }
    else       { s = ei32[e];   d = ei32[EE+e]; }
  } else { s = e - EE; d = s; }
}

__global__ __launch_bounds__(256) void k_build(const int* __restrict__ ei32, const int* __restrict__ mode,
    unsigned* __restrict__ rowbits, unsigned* __restrict__ colbits, unsigned* __restrict__ cnt){
  int e = blockIdx.x*256 + threadIdx.x;
  if(e >= EP) return;
  int m = *mode, s, d;
  edge_sd(ei32, m, e, s, d);
  atomicOr(&rowbits[s*NWORDS + (d>>5)], 1u<<(d&31));
  atomicOr(&colbits[d*NWORDS + (s>>5)], 1u<<(s&31));
  atomicAdd(&cnt[d], 1u);
}

__global__ __launch_bounds__(256) void k_scan(const unsigned* __restrict__ cnt, unsigned* __restrict__ rowptr){
  __shared__ unsigned part[256];
  int t = threadIdx.x;
  unsigned loc[16]; unsigned s = 0;
#pragma unroll
  for(int i=0;i<16;i++){ loc[i]=cnt[t*16+i]; s+=loc[i]; }
  part[t]=s; __syncthreads();
  for(int off=1;off<256;off<<=1){
    unsigned v = (t>=off)? part[t-off] : 0u;
    __syncthreads();
    part[t]+=v;
    __syncthreads();
  }
  unsigned run = (t==0)? 0u : part[t-1];
#pragma unroll
  for(int i=0;i<16;i++){ rowptr[t*16+i]=run; run+=loc[i]; }
  if(t==255) rowptr[NN]=run;
}

__global__ __launch_bounds__(256) void k_fill(const int* __restrict__ ei32, const int* __restrict__ mode,
    const unsigned* __restrict__ rowptr, unsigned* __restrict__ fill,
    unsigned* __restrict__ csr_src, unsigned* __restrict__ csr_eid){
  int e = blockIdx.x*256 + threadIdx.x;
  if(e >= EP) return;
  int m = *mode, s, d;
  edge_sd(ei32, m, e, s, d);
  unsigned pos = rowptr[d] + atomicAdd(&fill[d], 1u);
  csr_src[pos]=(unsigned)s; csr_eid[pos]=(unsigned)e;
}

// v1 = A @ 1 (out-degree incl. self loop)
__global__ __launch_bounds__(256) void k_deg(const unsigned* __restrict__ rowbits, float* __restrict__ v1){
  int node = blockIdx.x*4 + (threadIdx.x>>6);
  int lane = threadIdx.x & 63;
  unsigned w0 = rowbits[node*NWORDS + 2*lane];
  unsigned w1 = rowbits[node*NWORDS + 2*lane + 1];
  int c = __popc(w0) + __popc(w1);
  c = wredSumi(c);
  if(lane==0) v1[node] = (float)c;
}

// vout = A @ vin
__global__ __launch_bounds__(256) void k_mv(const unsigned* __restrict__ rowbits,
    const float* __restrict__ vin, float* __restrict__ vout){
  int node = blockIdx.x*4 + (threadIdx.x>>6);
  int lane = threadIdx.x & 63;
  float sum = 0.f;
  unsigned w = rowbits[node*NWORDS + 2*lane]; int b0 = lane*64;
  while(w){ int b=__ffs(w)-1; sum += vin[b0+b]; w &= w-1; }
  w = rowbits[node*NWORDS + 2*lane + 1]; b0 = lane*64 + 32;
  while(w){ int b=__ffs(w)-1; sum += vin[b0+b]; w &= w-1; }
  sum = wredSumf(sum);
  if(lane==0) vout[node] = sum;
}

// per-dst: bit-plane counters g[k]=A^2[k,d] in REGISTERS (8 planes x 2 words/lane);
// per in-edge (s,d): A^3[s,d] = sum_p popc(rowbits[s] & plane_p) << p; mw = A3/max(rowsum3[s],1)
__global__ __launch_bounds__(64) void k_motif(const unsigned* __restrict__ rowbits, const unsigned* __restrict__ colbits,
    const unsigned* __restrict__ rowptr, const unsigned* __restrict__ csr_src, const unsigned* __restrict__ csr_eid,
    const float* __restrict__ v3, float* __restrict__ mw){
  int d = blockIdx.x;
  int lane = threadIdx.x;
  __shared__ unsigned short nbr[1024];   // indeg max ~70 << 1024
  __shared__ int cntL;
  if(lane==0) cntL=0;
  __syncthreads();
  // in-neighbor list of d (unique, from colbits)
  {
    unsigned w = colbits[d*NWORDS + 2*lane]; int b0 = lane*64;
    while(w){ int b=__ffs(w)-1; int pos=atomicAdd(&cntL,1); nbr[pos]=(unsigned short)(b0+b); w&=w-1; }
    w = colbits[d*NWORDS + 2*lane + 1]; b0 = lane*64 + 32;
    while(w){ int b=__ffs(w)-1; int pos=atomicAdd(&cntL,1); nbr[pos]=(unsigned short)(b0+b); w&=w-1; }
  }
  __syncthreads();
  int m = cntL;
  // bit-plane ripple-carry accumulate: g[k] += bit_k(col l) for each in-neighbor l
  unsigned gp[8][2];
#pragma unroll
  for(int p=0;p<8;p++){ gp[p][0]=0u; gp[p][1]=0u; }
  for(int t0=0;t0<m;t0+=4){
    unsigned xa[4], xb[4];
#pragma unroll
    for(int j=0;j<4;j++){
      int tt=t0+j;
      if(tt<m){ int l = nbr[tt]; xa[j]=colbits[l*NWORDS+2*lane]; xb[j]=colbits[l*NWORDS+2*lane+1]; }
      else    { xa[j]=0u; xb[j]=0u; }
    }
#pragma unroll
    for(int j=0;j<4;j++){
      unsigned c = xa[j];
#pragma unroll
      for(int p=0;p<8;p++){ unsigned cy = gp[p][0] & c; gp[p][0] ^= c; c = cy; }
      c = xb[j];
#pragma unroll
      for(int p=0;p<8;p++){ unsigned cy = gp[p][1] & c; gp[p][1] ^= c; c = cy; }
    }
  }
  // edge phase: 4 edges per iteration, packed 2x16-bit wave reduction (totals <= ~4600 < 2^16)
  unsigned base = rowptr[d], deg = rowptr[d+1]-base;
  for(unsigned i0=0;i0<deg;i0+=4){
    unsigned sidx[4], ra[4], rb[4];
#pragma unroll
    for(int j=0;j<4;j++){
      unsigned ii = (i0+j < deg) ? (i0+j) : (deg-1);
      sidx[j] = csr_src[base+ii];
    }
#pragma unroll
    for(int j=0;j<4;j++){ ra[j]=rowbits[sidx[j]*NWORDS+2*lane]; rb[j]=rowbits[sidx[j]*NWORDS+2*lane+1]; }
    int sum[4];
#pragma unroll
    for(int j=0;j<4;j++){
      int s=0;
#pragma unroll
      for(int p=0;p<8;p++)
        s += (__popc(ra[j]&gp[p][0]) + __popc(rb[j]&gp[p][1])) << p;
      sum[j]=s;
    }
    int pk0 = sum[0] | (sum[1]<<16);
    int pk1 = sum[2] | (sum[3]<<16);
    pk0 = wredSumi(pk0); pk1 = wredSumi(pk1);
    if(lane==0){
      int ss[4] = { pk0 & 0xFFFF, (pk0>>16)&0xFFFF, pk1 & 0xFFFF, (pk1>>16)&0xFFFF };
#pragma unroll
      for(int j=0;j<4;j++){
        unsigned idx = i0+j;
        if(idx<deg)
          mw[csr_eid[base+idx]] = (float)ss[j] / fmaxf(v3[csr_src[base+idx]], 1.0f);
      }
    }
  }
}

// ---- f32 tiled GEMM: C[M,N] = A[M,K] @ B[K,N]; M,N mult of 64, K mult of 16 ----
#define GBM 64
#define GBN 64
#define GBK 16
__global__ __launch_bounds__(256) void k_gemm(const float* __restrict__ A, const float* __restrict__ B,
    float* __restrict__ C, int M, int N, int K){
  __shared__ float As[GBK][68];
  __shared__ float Bs[GBK][68];
  int bm = blockIdx.y*GBM, bn = blockIdx.x*GBN;
  int t = threadIdx.x;
  int tm = t>>4, tn = t&15;
  float acc[4][4];
#pragma unroll
  for(int i=0;i<4;i++)
#pragma unroll
    for(int j=0;j<4;j++) acc[i][j]=0.f;
  for(int k0=0;k0<K;k0+=GBK){
    {
      int mm = t>>2, kq = t&3;
      const float4 av = *(const float4*)&A[(size_t)(bm+mm)*K + k0 + kq*4];
      As[kq*4+0][mm]=av.x; As[kq*4+1][mm]=av.y; As[kq*4+2][mm]=av.z; As[kq*4+3][mm]=av.w;
      int kb = t>>4, nq = t&15;
      const float4 bv = *(const float4*)&B[(size_t)(k0+kb)*N + bn + nq*4];
      *(float4*)&Bs[kb][nq*4] = bv;
    }
    __syncthreads();
#pragma unroll
    for(int k=0;k<GBK;k++){
      const float4 a = *(const float4*)&As[k][tm*4];
      const float4 b = *(const float4*)&Bs[k][tn*4];
      float aa[4]={a.x,a.y,a.z,a.w}, bb[4]={b.x,b.y,b.z,b.w};
#pragma unroll
      for(int i=0;i<4;i++)
#pragma unroll
        for(int j=0;j<4;j++) acc[i][j] += aa[i]*bb[j];
    }
    __syncthreads();
  }
#pragma unroll
  for(int i=0;i<4;i++){
    float4 o = {acc[i][0],acc[i][1],acc[i][2],acc[i][3]};
    *(float4*)&C[(size_t)(bm+tm*4+i)*N + bn + tn*4] = o;
  }
}

// per-node attention logit dots, layer 1 (8 heads x 64 ch)
__global__ __launch_bounds__(512) void k_attn1(const float* __restrict__ hpre, const float* __restrict__ as1,
    const float* __restrict__ ad1, float* __restrict__ asrc, float* __restrict__ adst){
  int n = blockIdx.x; int t = threadIdx.x; int lane = t&63; int h = t>>6;
  float v = hpre[n*C1 + t];
  float p1 = v*as1[t], p2 = v*ad1[t];
  p1 = wredSumf(p1); p2 = wredSumf(p2);
  if(lane==0){ asrc[n*H1+h]=p1; adst[n*H1+h]=p2; }
}

// layer-1 dual segment-softmax + aggregation + bias + ELU
__global__ __launch_bounds__(128) void k_layer1(const unsigned* __restrict__ rowptr, const unsigned* __restrict__ csr_src,
    const unsigned* __restrict__ csr_eid, const float* __restrict__ mw, const float* __restrict__ asrc,
    const float* __restrict__ adst, const float* __restrict__ hpre, const float* __restrict__ b1,
    float* __restrict__ h1){
  int n = blockIdx.x;
  int tid = threadIdx.x, lane = tid&63, wv = tid>>6;
  unsigned base = rowptr[n], deg = rowptr[n+1]-base;
  __shared__ float adsts[8];
  __shared__ float r1[2][8], r2[2][8];
  __shared__ float sM1[8], sM2[8], sS1[8], sS2[8];
  if(tid<8) adsts[tid] = adst[n*H1+tid];
  __syncthreads();
  float ad[8];
#pragma unroll
  for(int h=0;h<8;h++) ad[h]=adsts[h];
  float m1[8], m2[8];
#pragma unroll
  for(int h=0;h<8;h++){ m1[h]=-3.0e38f; m2[h]=-3.0e38f; }
  for(unsigned i=tid;i<deg;i+=128){
    unsigned s = csr_src[base+i];
    float mwv = mw[csr_eid[base+i]];
    const float4 a0 = *(const float4*)&asrc[s*H1];
    const float4 a1 = *(const float4*)&asrc[s*H1+4];
    float as8[8]={a0.x,a0.y,a0.z,a0.w,a1.x,a1.y,a1.z,a1.w};
#pragma unroll
    for(int h=0;h<8;h++){
      float ev = as8[h]+ad[h];
      float el = ev>=0.f? ev : 0.2f*ev;
      float evm = ev*mwv;
      float em = evm>=0.f? evm : 0.2f*evm;
      m1[h]=fmaxf(m1[h],el); m2[h]=fmaxf(m2[h],em);
    }
  }
#pragma unroll
  for(int h=0;h<8;h++){ m1[h]=wredMaxf(m1[h]); m2[h]=wredMaxf(m2[h]); }
  if(lane==0){
#pragma unroll
    for(int h=0;h<8;h++){ r1[wv][h]=m1[h]; r2[wv][h]=m2[h]; }
  }
  __syncthreads();
  if(tid<8){ sM1[tid]=fmaxf(r1[0][tid],r1[1][tid]); sM2[tid]=fmaxf(r2[0][tid],r2[1][tid]); }
  __syncthreads();
  float s1[8], s2[8];
#pragma unroll
  for(int h=0;h<8;h++){ s1[h]=0.f; s2[h]=0.f; }
  for(unsigned i=tid;i<deg;i+=128){
    unsigned s = csr_src[base+i];
    float mwv = mw[csr_eid[base+i]];
    const float4 a0 = *(const float4*)&asrc[s*H1];
    const float4 a1 = *(const float4*)&asrc[s*H1+4];
    float as8[8]={a0.x,a0.y,a0.z,a0.w,a1.x,a1.y,a1.z,a1.w};
#pragma unroll
    for(int h=0;h<8;h++){
      float ev = as8[h]+ad[h];
      float el = ev>=0.f? ev : 0.2f*ev;
      float evm = ev*mwv;
      float em = evm>=0.f? evm : 0.2f*evm;
      s1[h] += expf(el - sM1[h]);
      s2[h] += expf(em - sM2[h]);
    }
  }
#pragma unroll
  for(int h=0;h<8;h++){ s1[h]=wredSumf(s1[h]); s2[h]=wredSumf(s2[h]); }
  __syncthreads();   // r1/r2 reads (for sM) done; safe to overwrite
  if(lane==0){
#pragma unroll
    for(int h=0;h<8;h++){ r1[wv][h]=s1[h]; r2[wv][h]=s2[h]; }
  }
  __syncthreads();
  if(tid<8){ sS1[tid]=r1[0][tid]+r1[1][tid]+1e-16f; sS2[tid]=r2[0][tid]+r2[1][tid]+1e-16f; }
  __syncthreads();
  // aggregation: thread owns 4 channels
  int c0 = tid*4; int h = tid>>4;
  float adh = adsts[h];
  float M1h = sM1[h], M2h = sM2[h], S1h = sS1[h], S2h = sS2[h];
  float4 acc = {0.f,0.f,0.f,0.f};
  for(unsigned i=0;i<deg;i++){
    unsigned s = csr_src[base+i];
    float mwv = mw[csr_eid[base+i]];
    float ev = asrc[s*H1+h] + adh;
    float el = ev>=0.f? ev : 0.2f*ev;
    float evm = ev*mwv;
    float em = evm>=0.f? evm : 0.2f*evm;
    float alpha = 0.5f*(expf(el-M1h)/S1h + expf(em-M2h)/S2h);
    const float4 hv = *(const float4*)&hpre[s*C1 + c0];
    acc.x += alpha*hv.x; acc.y += alpha*hv.y; acc.z += alpha*hv.z; acc.w += alpha*hv.w;
  }
  const float4 bv = *(const float4*)&b1[c0];
  float4 o;
  float vx = acc.x+bv.x; o.x = vx>0.f? vx : expm1f(vx);
  float vy = acc.y+bv.y; o.y = vy>0.f? vy : expm1f(vy);
  float vz = acc.z+bv.z; o.z = vz>0.f? vz : expm1f(vz);
  float vw = acc.w+bv.w; o.w = vw>0.f? vw : expm1f(vw);
  *(float4*)&h1[n*C1 + c0] = o;
}

// per-node attention logit dots, layer 2 (1 head x 256 ch)
__global__ __launch_bounds__(64) void k_attn2(const float* __restrict__ h2, const float* __restrict__ as2,
    const float* __restrict__ ad2, float* __restrict__ asrc, float* __restrict__ adst){
  int n = blockIdx.x; int lane = threadIdx.x;
  const float4 hv = *(const float4*)&h2[n*C2 + lane*4];
  const float4 av = *(const float4*)&as2[lane*4];
  const float4 dv = *(const float4*)&ad2[lane*4];
  float p1 = hv.x*av.x + hv.y*av.y + hv.z*av.z + hv.w*av.w;
  float p2 = hv.x*dv.x + hv.y*dv.y + hv.z*dv.z + hv.w*dv.w;
  p1 = wredSumf(p1); p2 = wredSumf(p2);
  if(lane==0){ asrc[n]=p1; adst[n]=p2; }
}

// layer-2: softmax + aggregation + residual + bias -> d_out
__global__ __launch_bounds__(64) void k_layer2(const unsigned* __restrict__ rowptr, const unsigned* __restrict__ csr_src,
    const unsigned* __restrict__ csr_eid, const float* __restrict__ mw, const float* __restrict__ asrc,
    const float* __restrict__ adst, const float* __restrict__ h2, const float* __restrict__ res,
    const float* __restrict__ b2, float* __restrict__ out){
  int n = blockIdx.x; int lane = threadIdx.x;
  unsigned base = rowptr[n], deg = rowptr[n+1]-base;
  float ad = adst[n];
  float m1=-3.0e38f, m2=-3.0e38f;
  for(unsigned i=lane;i<deg;i+=64){
    unsigned s = csr_src[base+i];
    float mwv = mw[csr_eid[base+i]];
    float ev = asrc[s] + ad;
    float el = ev>=0.f? ev : 0.2f*ev;
    float evm = ev*mwv;
    float em = evm>=0.f? evm : 0.2f*evm;
    m1=fmaxf(m1,el); m2=fmaxf(m2,em);
  }
  m1 = wredMaxf(m1); m2 = wredMaxf(m2);
  float s1=0.f, s2=0.f;
  for(unsigned i=lane;i<deg;i+=64){
    unsigned s = csr_src[base+i];
    float mwv = mw[csr_eid[base+i]];
    float ev = asrc[s] + ad;
    float el = ev>=0.f? ev : 0.2f*ev;
    float evm = ev*mwv;
    float em = evm>=0.f? evm : 0.2f*evm;
    s1 += expf(el-m1); s2 += expf(em-m2);
  }
  s1 = wredSumf(s1) + 1e-16f;
  s2 = wredSumf(s2) + 1e-16f;
  int c0 = lane*4;
  float4 acc = {0.f,0.f,0.f,0.f};
  for(unsigned i=0;i<deg;i++){
    unsigned s = csr_src[base+i];
    float mwv = mw[csr_eid[base+i]];
    float ev = asrc[s] + ad;
    float el = ev>=0.f? ev : 0.2f*ev;
    float evm = ev*mwv;
    float em = evm>=0.f? evm : 0.2f*evm;
    float alpha = 0.5f*(expf(el-m1)/s1 + expf(em-m2)/s2);
    const float4 hv = *(const float4*)&h2[s*C2 + c0];
    acc.x += alpha*hv.x; acc.y += alpha*hv.y; acc.z += alpha*hv.z; acc.w += alpha*hv.w;
  }
  const float4 rv = *(const float4*)&res[n*C2 + c0];
  const float4 bv = *(const float4*)&b2[c0];
  float4 o = {acc.x+rv.x+bv.x, acc.y+rv.y+bv.y, acc.z+rv.z+bv.z, acc.w+rv.w+bv.w};
  *(float4*)&out[n*C2 + c0] = o;
}

extern "C" void kernel_launch(void* const* d_in, const int* in_sizes, int n_in,
                              void* d_out, int out_size, void* d_ws, size_t ws_size,
                              hipStream_t stream) {
  const float* x    = (const float*)d_in[0];
  const int*   ei32 = (const int*)d_in[1];     // int64 vs int32 auto-detected
  const float* W1   = (const float*)d_in[2];
  const float* as1  = (const float*)d_in[3];
  const float* ad1  = (const float*)d_in[4];
  const float* b1   = (const float*)d_in[5];
  const float* W2   = (const float*)d_in[6];
  const float* as2  = (const float*)d_in[7];
  const float* ad2  = (const float*)d_in[8];
  const float* b2   = (const float*)d_in[9];
  const float* resW2= (const float*)d_in[10];
  float* out = (float*)d_out;

  char* p = (char*)d_ws;
  auto alloc = [&](size_t b){ void* r=(void*)p; p += (b + 255) & ~(size_t)255; return r; };
  unsigned* rowbits = (unsigned*)alloc((size_t)NN*NWORDS*4);   // 2MB
  unsigned* colbits = (unsigned*)alloc((size_t)NN*NWORDS*4);   // 2MB (contiguous with rowbits)
  unsigned* cnt     = (unsigned*)alloc(NN*4);
  unsigned* fill    = (unsigned*)alloc(NN*4);                  // contiguous with cnt
  unsigned* rowptr  = (unsigned*)alloc((NN+4)*4);
  float* v1 = (float*)alloc(NN*4);
  float* v2 = (float*)alloc(NN*4);
  float* v3 = (float*)alloc(NN*4);
  unsigned* csr_src = (unsigned*)alloc((size_t)EP*4);
  unsigned* csr_eid = (unsigned*)alloc((size_t)EP*4);
  float* mw   = (float*)alloc((size_t)EP*4);
  float* asrc1= (float*)alloc(NN*H1*4);
  float* adst1= (float*)alloc(NN*H1*4);
  float* hpre = (float*)alloc((size_t)NN*C1*4);   // 8MB; reused as h2+res after k_layer1
  float* h1   = (float*)alloc((size_t)NN*C1*4);   // 8MB
  float* asrc2= (float*)alloc(NN*4);
  float* adst2= (float*)alloc(NN*4);
  int* mode   = (int*)alloc(256);
  // hpre is dead after k_layer1 -> reuse its 8MB for h2 (4MB) + res (4MB)
  float* h2  = hpre;
  float* res = hpre + (size_t)NN*C2;

  hipMemsetAsync(rowbits, 0, (size_t)NN*NWORDS*4*2, stream);   // rowbits+colbits
  hipMemsetAsync(cnt, 0, (size_t)NN*4*2, stream);              // cnt+fill

  k_detect<<<1,256,0,stream>>>(ei32, mode);
  k_build<<<(EP+255)/256,256,0,stream>>>(ei32, mode, rowbits, colbits, cnt);
  k_scan<<<1,256,0,stream>>>(cnt, rowptr);
  k_fill<<<(EP+255)/256,256,0,stream>>>(ei32, mode, rowptr, fill, csr_src, csr_eid);
  k_deg<<<NN/4,256,0,stream>>>(rowbits, v1);
  k_mv<<<NN/4,256,0,stream>>>(rowbits, v1, v2);
  k_mv<<<NN/4,256,0,stream>>>(rowbits, v2, v3);
  k_motif<<<NN,64,0,stream>>>(rowbits, colbits, rowptr, csr_src, csr_eid, v3, mw);

  k_gemm<<<dim3(C1/GBN, NN/GBM),256,0,stream>>>(x, W1, hpre, NN, C1, C1);
  k_attn1<<<NN,512,0,stream>>>(hpre, as1, ad1, asrc1, adst1);
  k_layer1<<<NN,128,0,stream>>>(rowptr, csr_src, csr_eid, mw, asrc1, adst1, hpre, b1, h1);

  k_gemm<<<dim3(C2/GBN, NN/GBM),256,0,stream>>>(h1, W2, h2, NN, C2, C1);
  k_gemm<<<dim3(C2/GBN, NN/GBM),256,0,stream>>>(h1, resW2, res, NN, C2, C1);
  k_attn2<<<NN,64,0,stream>>>(h2, as2, ad2, asrc2, adst2);
  k_layer2<<<NN,64,0,stream>>>(rowptr, csr_src, csr_eid, mw, asrc2, adst2, h2, res, b2, out);
}

// Round 5
// 314.767 us; speedup vs baseline: 1.3872x; 1.1564x over previous
//
#include <hip/hip_runtime.h>
#include <hip/hip_bf16.h>
#include <math.h>

#define NN 4096
#define EE 131072
#define EP (EE + NN)     // 135168 edges incl. self loops
#define C1 512
#define H1 8
#define C2 256
#define NWORDS 128       // 4096 bits / 32

__device__ __forceinline__ float wredMaxf(float v){
#pragma unroll
  for(int o=32;o;o>>=1) v = fmaxf(v, __shfl_xor(v,o));
  return v;
}
__device__ __forceinline__ float wredSumf(float v){
#pragma unroll
  for(int o=32;o;o>>=1) v += __shfl_xor(v,o);
  return v;
}
__device__ __forceinline__ int wredSumi(int v){
#pragma unroll
  for(int o=32;o;o>>=1) v += __shfl_xor(v,o);
  return v;
}

// ---- edge dtype detection: int64 => high 32-bit words are all zero ----
__global__ __launch_bounds__(256) void k_detect(const int* __restrict__ ei32, int* __restrict__ mode){
  __shared__ int any;
  if(threadIdx.x==0) any = 0;
  __syncthreads();
  int nz = 0;
  for(int i=threadIdx.x;i<2048;i+=256) nz |= (ei32[2*i+1] != 0);
  if(nz) atomicOr(&any, 1);
  __syncthreads();
  if(threadIdx.x==0) *mode = any;   // 1 => int32, 0 => int64
}

__device__ __forceinline__ void edge_sd(const int* ei32, int mode, int e, int& s, int& d){
  if(e < EE){
    if(mode==0){ s = ei32[2*e]; d = ei32[2*(EE+e)]; }
    else       { s = ei32[e];   d = ei32[EE+e]; }
  } else { s = e - EE; d = s; }
}

__global__ __launch_bounds__(256) void k_build(const int* __restrict__ ei32, const int* __restrict__ mode,
    unsigned* __restrict__ rowbits, unsigned* __restrict__ colbits, unsigned* __restrict__ cnt){
  int e = blockIdx.x*256 + threadIdx.x;
  if(e >= EP) return;
  int m = *mode, s, d;
  edge_sd(ei32, m, e, s, d);
  atomicOr(&rowbits[s*NWORDS + (d>>5)], 1u<<(d&31));
  atomicOr(&colbits[d*NWORDS + (s>>5)], 1u<<(s&31));
  atomicAdd(&cnt[d], 1u);
}

__global__ __launch_bounds__(256) void k_scan(const unsigned* __restrict__ cnt, unsigned* __restrict__ rowptr){
  __shared__ unsigned part[256];
  int t = threadIdx.x;
  unsigned loc[16]; unsigned s = 0;
#pragma unroll
  for(int i=0;i<16;i++){ loc[i]=cnt[t*16+i]; s+=loc[i]; }
  part[t]=s; __syncthreads();
  for(int off=1;off<256;off<<=1){
    unsigned v = (t>=off)? part[t-off] : 0u;
    __syncthreads();
    part[t]+=v;
    __syncthreads();
  }
  unsigned run = (t==0)? 0u : part[t-1];
#pragma unroll
  for(int i=0;i<16;i++){ rowptr[t*16+i]=run; run+=loc[i]; }
  if(t==255) rowptr[NN]=run;
}

__global__ __launch_bounds__(256) void k_fill(const int* __restrict__ ei32, const int* __restrict__ mode,
    const unsigned* __restrict__ rowptr, unsigned* __restrict__ fill,
    unsigned* __restrict__ csr_src){
  int e = blockIdx.x*256 + threadIdx.x;
  if(e >= EP) return;
  int m = *mode, s, d;
  edge_sd(ei32, m, e, s, d);
  unsigned pos = rowptr[d] + atomicAdd(&fill[d], 1u);
  csr_src[pos]=(unsigned)s;
}

// v1 = A @ 1 (out-degree incl. self loop)
__global__ __launch_bounds__(256) void k_deg(const unsigned* __restrict__ rowbits, float* __restrict__ v1){
  int node = blockIdx.x*4 + (threadIdx.x>>6);
  int lane = threadIdx.x & 63;
  unsigned w0 = rowbits[node*NWORDS + 2*lane];
  unsigned w1 = rowbits[node*NWORDS + 2*lane + 1];
  int c = __popc(w0) + __popc(w1);
  c = wredSumi(c);
  if(lane==0) v1[node] = (float)c;
}

// vout = A @ vin
__global__ __launch_bounds__(256) void k_mv(const unsigned* __restrict__ rowbits,
    const float* __restrict__ vin, float* __restrict__ vout){
  int node = blockIdx.x*4 + (threadIdx.x>>6);
  int lane = threadIdx.x & 63;
  float sum = 0.f;
  unsigned w = rowbits[node*NWORDS + 2*lane]; int b0 = lane*64;
  while(w){ int b=__ffs(w)-1; sum += vin[b0+b]; w &= w-1; }
  w = rowbits[node*NWORDS + 2*lane + 1]; b0 = lane*64 + 32;
  while(w){ int b=__ffs(w)-1; sum += vin[b0+b]; w &= w-1; }
  sum = wredSumf(sum);
  if(lane==0) vout[node] = sum;
}

// per-dst: bit-plane counters g[k]=A^2[k,d] in REGISTERS (8 planes x 2 words/lane);
// per in-edge (s,d): A^3[s,d] = sum_p popc(rowbits[s] & plane_p) << p; mwc[base+i] = A3/max(rowsum3[s],1)
__global__ __launch_bounds__(64) void k_motif(const unsigned* __restrict__ rowbits, const unsigned* __restrict__ colbits,
    const unsigned* __restrict__ rowptr, const unsigned* __restrict__ csr_src,
    const float* __restrict__ v3, float* __restrict__ mwc){
  int d = blockIdx.x;
  int lane = threadIdx.x;
  __shared__ unsigned short nbr[1024];   // indeg max ~70 << 1024
  __shared__ int cntL;
  if(lane==0) cntL=0;
  __syncthreads();
  // in-neighbor list of d (unique, from colbits)
  {
    unsigned w = colbits[d*NWORDS + 2*lane]; int b0 = lane*64;
    while(w){ int b=__ffs(w)-1; int pos=atomicAdd(&cntL,1); nbr[pos]=(unsigned short)(b0+b); w&=w-1; }
    w = colbits[d*NWORDS + 2*lane + 1]; b0 = lane*64 + 32;
    while(w){ int b=__ffs(w)-1; int pos=atomicAdd(&cntL,1); nbr[pos]=(unsigned short)(b0+b); w&=w-1; }
  }
  __syncthreads();
  int m = cntL;
  // bit-plane ripple-carry accumulate: g[k] += bit_k(col l) for each in-neighbor l
  unsigned gp[8][2];
#pragma unroll
  for(int p=0;p<8;p++){ gp[p][0]=0u; gp[p][1]=0u; }
  for(int t0=0;t0<m;t0+=4){
    unsigned xa[4], xb[4];
#pragma unroll
    for(int j=0;j<4;j++){
      int tt=t0+j;
      if(tt<m){ int l = nbr[tt]; xa[j]=colbits[l*NWORDS+2*lane]; xb[j]=colbits[l*NWORDS+2*lane+1]; }
      else    { xa[j]=0u; xb[j]=0u; }
    }
#pragma unroll
    for(int j=0;j<4;j++){
      unsigned c = xa[j];
#pragma unroll
      for(int p=0;p<8;p++){ unsigned cy = gp[p][0] & c; gp[p][0] ^= c; c = cy; }
      c = xb[j];
#pragma unroll
      for(int p=0;p<8;p++){ unsigned cy = gp[p][1] & c; gp[p][1] ^= c; c = cy; }
    }
  }
  // edge phase: 4 edges per iteration, packed 2x16-bit wave reduction (totals <= ~4600 < 2^16)
  unsigned base = rowptr[d], deg = rowptr[d+1]-base;
  for(unsigned i0=0;i0<deg;i0+=4){
    unsigned sidx[4], ra[4], rb[4];
#pragma unroll
    for(int j=0;j<4;j++){
      unsigned ii = (i0+j < deg) ? (i0+j) : (deg-1);
      sidx[j] = csr_src[base+ii];
    }
#pragma unroll
    for(int j=0;j<4;j++){ ra[j]=rowbits[sidx[j]*NWORDS+2*lane]; rb[j]=rowbits[sidx[j]*NWORDS+2*lane+1]; }
    int sum[4];
#pragma unroll
    for(int j=0;j<4;j++){
      int s=0;
#pragma unroll
      for(int p=0;p<8;p++)
        s += (__popc(ra[j]&gp[p][0]) + __popc(rb[j]&gp[p][1])) << p;
      sum[j]=s;
    }
    int pk0 = sum[0] | (sum[1]<<16);
    int pk1 = sum[2] | (sum[3]<<16);
    pk0 = wredSumi(pk0); pk1 = wredSumi(pk1);
    if(lane==0){
      int ss[4] = { pk0 & 0xFFFF, (pk0>>16)&0xFFFF, pk1 & 0xFFFF, (pk1>>16)&0xFFFF };
#pragma unroll
      for(int j=0;j<4;j++){
        unsigned idx = i0+j;
        if(idx<deg)
          mwc[base+idx] = (float)ss[j] / fmaxf(v3[csr_src[base+idx]], 1.0f);
      }
    }
  }
}

// ---- f32 tiled GEMM: C[M,N] = A[M,K] @ B[K,N]; M,N mult of 64, K mult of 16 ----
#define GBM 64
#define GBN 64
#define GBK 16
__global__ __launch_bounds__(256) void k_gemm(const float* __restrict__ A, const float* __restrict__ B,
    float* __restrict__ C, int M, int N, int K){
  __shared__ float As[GBK][68];
  __shared__ float Bs[GBK][68];
  int bm = blockIdx.y*GBM, bn = blockIdx.x*GBN;
  int t = threadIdx.x;
  int tm = t>>4, tn = t&15;
  float acc[4][4];
#pragma unroll
  for(int i=0;i<4;i++)
#pragma unroll
    for(int j=0;j<4;j++) acc[i][j]=0.f;
  for(int k0=0;k0<K;k0+=GBK){
    {
      int mm = t>>2, kq = t&3;
      const float4 av = *(const float4*)&A[(size_t)(bm+mm)*K + k0 + kq*4];
      As[kq*4+0][mm]=av.x; As[kq*4+1][mm]=av.y; As[kq*4+2][mm]=av.z; As[kq*4+3][mm]=av.w;
      int kb = t>>4, nq = t&15;
      const float4 bv = *(const float4*)&B[(size_t)(k0+kb)*N + bn + nq*4];
      *(float4*)&Bs[kb][nq*4] = bv;
    }
    __syncthreads();
#pragma unroll
    for(int k=0;k<GBK;k++){
      const float4 a = *(const float4*)&As[k][tm*4];
      const float4 b = *(const float4*)&Bs[k][tn*4];
      float aa[4]={a.x,a.y,a.z,a.w}, bb[4]={b.x,b.y,b.z,b.w};
#pragma unroll
      for(int i=0;i<4;i++)
#pragma unroll
        for(int j=0;j<4;j++) acc[i][j] += aa[i]*bb[j];
    }
    __syncthreads();
  }
#pragma unroll
  for(int i=0;i<4;i++){
    float4 o = {acc[i][0],acc[i][1],acc[i][2],acc[i][3]};
    *(float4*)&C[(size_t)(bm+tm*4+i)*N + bn + tn*4] = o;
  }
}

// per-node attention logit dots, layer 1 (8 heads x 64 ch)
__global__ __launch_bounds__(512) void k_attn1(const float* __restrict__ hpre, const float* __restrict__ as1,
    const float* __restrict__ ad1, float* __restrict__ asrc, float* __restrict__ adst){
  int n = blockIdx.x; int t = threadIdx.x; int lane = t&63; int h = t>>6;
  float v = hpre[n*C1 + t];
  float p1 = v*as1[t], p2 = v*ad1[t];
  p1 = wredSumf(p1); p2 = wredSumf(p2);
  if(lane==0){ asrc[n*H1+h]=p1; adst[n*H1+h]=p2; }
}

// layer-1: flash-style single-sweep dual segment-softmax + aggregation + bias + ELU
// block = 128 threads (2 waves); chunk = 128 edges staged via LDS; thread owns 4 channels, head = tid>>4
__global__ __launch_bounds__(128) void k_layer1(const unsigned* __restrict__ rowptr, const unsigned* __restrict__ csr_src,
    const float* __restrict__ mwc, const float* __restrict__ asrc, const float* __restrict__ adst,
    const float* __restrict__ hpre, const float* __restrict__ b1, float* __restrict__ h1){
  int n = blockIdx.x;
  int tid = threadIdx.x, lane = tid&63, wv = tid>>6;
  unsigned base = rowptr[n], deg = rowptr[n+1]-base;
  __shared__ float a1s[128][9];   // +1 pad: stride-8 would be 16-way bank conflict on write
  __shared__ float a2s[128][9];
  __shared__ unsigned ssrc[128];
  __shared__ float red1[2][8], red2[2][8];
  __shared__ float snm1[8], snm2[8], sscl1[8], sscl2[8];
  __shared__ float sS1[8], sS2[8], sM1[8], sM2[8];
  __shared__ float adsts[8];
  if(tid<8){ adsts[tid]=adst[n*H1+tid]; sM1[tid]=-3.0e38f; sM2[tid]=-3.0e38f; sS1[tid]=0.f; sS2[tid]=0.f; }
  __syncthreads();
  int h = tid>>4;
  float4 acc1={0.f,0.f,0.f,0.f}, acc2={0.f,0.f,0.f,0.f};
  for(unsigned c0=0;c0<deg;c0+=128){
    int csz = (int)min(128u, deg-c0);
    bool act = (tid < csz);
    // phase A: logits for this chunk (thread = edge)
    float el[8], em[8];
    if(act){
      unsigned s = csr_src[base+c0+tid];
      ssrc[tid]=s;
      float mwv = mwc[base+c0+tid];
      const float4 a0v = *(const float4*)&asrc[s*H1];
      const float4 a1v = *(const float4*)&asrc[s*H1+4];
      float as8[8]={a0v.x,a0v.y,a0v.z,a0v.w,a1v.x,a1v.y,a1v.z,a1v.w};
#pragma unroll
      for(int hh=0;hh<8;hh++){
        float ev = as8[hh]+adsts[hh];
        el[hh] = ev>=0.f? ev : 0.2f*ev;
        float evm = ev*mwv;
        em[hh] = evm>=0.f? evm : 0.2f*evm;
      }
    } else {
#pragma unroll
      for(int hh=0;hh<8;hh++){ el[hh]=-3.0e38f; em[hh]=-3.0e38f; }
    }
    // chunk max -> new running max + rescale factors
    float mx1[8], mx2[8];
#pragma unroll
    for(int hh=0;hh<8;hh++){ mx1[hh]=wredMaxf(el[hh]); mx2[hh]=wredMaxf(em[hh]); }
    if(lane==0){
#pragma unroll
      for(int hh=0;hh<8;hh++){ red1[wv][hh]=mx1[hh]; red2[wv][hh]=mx2[hh]; }
    }
    __syncthreads();
    if(tid<8){
      float cm1 = fmaxf(red1[0][tid], red1[1][tid]);
      float cm2 = fmaxf(red2[0][tid], red2[1][tid]);
      float nm1 = fmaxf(sM1[tid], cm1), nm2 = fmaxf(sM2[tid], cm2);
      sscl1[tid] = expf(sM1[tid]-nm1); sscl2[tid] = expf(sM2[tid]-nm2);
      snm1[tid]=nm1; snm2[tid]=nm2;
      sM1[tid]=nm1;  sM2[tid]=nm2;
    }
    __syncthreads();
    // exp with new max, stage to LDS, chunk sums
    float s1l[8], s2l[8];
#pragma unroll
    for(int hh=0;hh<8;hh++){
      float a1v = act? expf(el[hh]-snm1[hh]) : 0.f;
      float a2v = act? expf(em[hh]-snm2[hh]) : 0.f;
      if(act){ a1s[tid][hh]=a1v; a2s[tid][hh]=a2v; }
      s1l[hh]=a1v; s2l[hh]=a2v;
    }
#pragma unroll
    for(int hh=0;hh<8;hh++){ s1l[hh]=wredSumf(s1l[hh]); s2l[hh]=wredSumf(s2l[hh]); }
    if(lane==0){
#pragma unroll
      for(int hh=0;hh<8;hh++){ red1[wv][hh]=s1l[hh]; red2[wv][hh]=s2l[hh]; }
    }
    __syncthreads();
    if(tid<8){
      sS1[tid] = sS1[tid]*sscl1[tid] + red1[0][tid]+red1[1][tid];
      sS2[tid] = sS2[tid]*sscl2[tid] + red2[0][tid]+red2[1][tid];
    }
    // rescale accumulators for the new max
    {
      float sc1 = sscl1[h], sc2 = sscl2[h];
      acc1.x*=sc1; acc1.y*=sc1; acc1.z*=sc1; acc1.w*=sc1;
      acc2.x*=sc2; acc2.y*=sc2; acc2.z*=sc2; acc2.w*=sc2;
    }
    // phase B: aggregate chunk, 4-edge batched gathers (thread owns channels tid*4..tid*4+3)
    for(int i0=0;i0<csz;i0+=4){
      int jn = min(4, csz-i0);
      unsigned sj[4]; float a1j[4], a2j[4];
#pragma unroll
      for(int j=0;j<4;j++){
        int ii = (j<jn)? i0+j : i0;
        sj[j]=ssrc[ii]; a1j[j]=a1s[ii][h]; a2j[j]=a2s[ii][h];
      }
      float4 hv[4];
#pragma unroll
      for(int j=0;j<4;j++) hv[j] = *(const float4*)&hpre[(size_t)sj[j]*C1 + tid*4];
#pragma unroll
      for(int j=0;j<4;j++){
        float w1 = (j<jn)? a1j[j] : 0.f;
        float w2 = (j<jn)? a2j[j] : 0.f;
        acc1.x += w1*hv[j].x; acc1.y += w1*hv[j].y; acc1.z += w1*hv[j].z; acc1.w += w1*hv[j].w;
        acc2.x += w2*hv[j].x; acc2.y += w2*hv[j].y; acc2.z += w2*hv[j].z; acc2.w += w2*hv[j].w;
      }
    }
    __syncthreads();   // protect ssrc/a1s/a2s/sS before next chunk
  }
  float r1 = 0.5f/(sS1[h]+1e-16f), r2 = 0.5f/(sS2[h]+1e-16f);
  int cc = tid*4;
  const float4 bv = *(const float4*)&b1[cc];
  float4 o;
  float vx = acc1.x*r1 + acc2.x*r2 + bv.x; o.x = vx>0.f? vx : expm1f(vx);
  float vy = acc1.y*r1 + acc2.y*r2 + bv.y; o.y = vy>0.f? vy : expm1f(vy);
  float vz = acc1.z*r1 + acc2.z*r2 + bv.z; o.z = vz>0.f? vz : expm1f(vz);
  float vw = acc1.w*r1 + acc2.w*r2 + bv.w; o.w = vw>0.f? vw : expm1f(vw);
  *(float4*)&h1[n*C1 + cc] = o;
}

// per-node attention logit dots, layer 2 (1 head x 256 ch)
__global__ __launch_bounds__(64) void k_attn2(const float* __restrict__ h2, const float* __restrict__ as2,
    const float* __restrict__ ad2, float* __restrict__ asrc, float* __restrict__ adst){
  int n = blockIdx.x; int lane = threadIdx.x;
  const float4 hv = *(const float4*)&h2[n*C2 + lane*4];
  const float4 av = *(const float4*)&as2[lane*4];
  const float4 dv = *(const float4*)&ad2[lane*4];
  float p1 = hv.x*av.x + hv.y*av.y + hv.z*av.z + hv.w*av.w;
  float p2 = hv.x*dv.x + hv.y*dv.y + hv.z*dv.z + hv.w*dv.w;
  p1 = wredSumf(p1); p2 = wredSumf(p2);
  if(lane==0){ asrc[n]=p1; adst[n]=p2; }
}

// layer-2: flash-style single-sweep + residual + bias -> d_out (1 wave, 1 head, 256 ch)
__global__ __launch_bounds__(64) void k_layer2(const unsigned* __restrict__ rowptr, const unsigned* __restrict__ csr_src,
    const float* __restrict__ mwc, const float* __restrict__ asrc, const float* __restrict__ adst,
    const float* __restrict__ h2, const float* __restrict__ res,
    const float* __restrict__ b2, float* __restrict__ out){
  int n = blockIdx.x; int lane = threadIdx.x;
  unsigned base = rowptr[n], deg = rowptr[n+1]-base;
  __shared__ float a1s[64], a2s[64];
  __shared__ unsigned ssrc[64];
  float ad = adst[n];
  float M1=-3.0e38f, M2=-3.0e38f, S1=0.f, S2=0.f;
  float4 acc1={0.f,0.f,0.f,0.f}, acc2={0.f,0.f,0.f,0.f};
  for(unsigned c0=0;c0<deg;c0+=64){
    int csz = (int)min(64u, deg-c0);
    bool act = (lane < csz);
    float el=-3.0e38f, em=-3.0e38f;
    if(act){
      unsigned s = csr_src[base+c0+lane];
      ssrc[lane]=s;
      float mwv = mwc[base+c0+lane];
      float ev = asrc[s] + ad;
      el = ev>=0.f? ev : 0.2f*ev;
      float evm = ev*mwv;
      em = evm>=0.f? evm : 0.2f*evm;
    }
    float nm1 = fmaxf(M1, wredMaxf(el));
    float nm2 = fmaxf(M2, wredMaxf(em));
    float sc1 = expf(M1-nm1), sc2 = expf(M2-nm2);
    M1=nm1; M2=nm2;
    float a1 = act? expf(el-nm1) : 0.f;
    float a2 = act? expf(em-nm2) : 0.f;
    if(act){ a1s[lane]=a1; a2s[lane]=a2; }
    S1 = S1*sc1 + wredSumf(a1);
    S2 = S2*sc2 + wredSumf(a2);
    acc1.x*=sc1; acc1.y*=sc1; acc1.z*=sc1; acc1.w*=sc1;
    acc2.x*=sc2; acc2.y*=sc2; acc2.z*=sc2; acc2.w*=sc2;
    __syncthreads();
    for(int i0=0;i0<csz;i0+=4){
      int jn = min(4, csz-i0);
      unsigned sj[4]; float a1j[4], a2j[4];
#pragma unroll
      for(int j=0;j<4;j++){
        int ii = (j<jn)? i0+j : i0;
        sj[j]=ssrc[ii]; a1j[j]=a1s[ii]; a2j[j]=a2s[ii];
      }
      float4 hv[4];
#pragma unroll
      for(int j=0;j<4;j++) hv[j] = *(const float4*)&h2[(size_t)sj[j]*C2 + lane*4];
#pragma unroll
      for(int j=0;j<4;j++){
        float w1 = (j<jn)? a1j[j] : 0.f;
        float w2 = (j<jn)? a2j[j] : 0.f;
        acc1.x += w1*hv[j].x; acc1.y += w1*hv[j].y; acc1.z += w1*hv[j].z; acc1.w += w1*hv[j].w;
        acc2.x += w2*hv[j].x; acc2.y += w2*hv[j].y; acc2.z += w2*hv[j].z; acc2.w += w2*hv[j].w;
      }
    }
    __syncthreads();
  }
  float r1 = 0.5f/(S1+1e-16f), r2 = 0.5f/(S2+1e-16f);
  int cc = lane*4;
  const float4 rv = *(const float4*)&res[n*C2 + cc];
  const float4 bv = *(const float4*)&b2[cc];
  float4 o = {acc1.x*r1 + acc2.x*r2 + rv.x + bv.x,
              acc1.y*r1 + acc2.y*r2 + rv.y + bv.y,
              acc1.z*r1 + acc2.z*r2 + rv.z + bv.z,
              acc1.w*r1 + acc2.w*r2 + rv.w + bv.w};
  *(float4*)&out[n*C2 + cc] = o;
}

extern "C" void kernel_launch(void* const* d_in, const int* in_sizes, int n_in,
                              void* d_out, int out_size, void* d_ws, size_t ws_size,
                              hipStream_t stream) {
  const float* x    = (const float*)d_in[0];
  const int*   ei32 = (const int*)d_in[1];     // int64 vs int32 auto-detected
  const float* W1   = (const float*)d_in[2];
  const float* as1  = (const float*)d_in[3];
  const float* ad1  = (const float*)d_in[4];
  const float* b1   = (const float*)d_in[5];
  const float* W2   = (const float*)d_in[6];
  const float* as2  = (const float*)d_in[7];
  const float* ad2  = (const float*)d_in[8];
  const float* b2   = (const float*)d_in[9];
  const float* resW2= (const float*)d_in[10];
  float* out = (float*)d_out;

  char* p = (char*)d_ws;
  auto alloc = [&](size_t b){ void* r=(void*)p; p += (b + 255) & ~(size_t)255; return r; };
  unsigned* rowbits = (unsigned*)alloc((size_t)NN*NWORDS*4);   // 2MB
  unsigned* colbits = (unsigned*)alloc((size_t)NN*NWORDS*4);   // 2MB (contiguous with rowbits)
  unsigned* cnt     = (unsigned*)alloc(NN*4);
  unsigned* fill    = (unsigned*)alloc(NN*4);                  // contiguous with cnt
  unsigned* rowptr  = (unsigned*)alloc((NN+4)*4);
  float* v1 = (float*)alloc(NN*4);
  float* v2 = (float*)alloc(NN*4);
  float* v3 = (float*)alloc(NN*4);
  unsigned* csr_src = (unsigned*)alloc((size_t)EP*4);
  float* mwc  = (float*)alloc((size_t)EP*4);      // motif weights in CSR order
  float* asrc1= (float*)alloc(NN*H1*4);
  float* adst1= (float*)alloc(NN*H1*4);
  float* hpre = (float*)alloc((size_t)NN*C1*4);   // 8MB; reused as h2+res after k_layer1
  float* h1   = (float*)alloc((size_t)NN*C1*4);   // 8MB
  float* asrc2= (float*)alloc(NN*4);
  float* adst2= (float*)alloc(NN*4);
  int* mode   = (int*)alloc(256);
  // hpre is dead after k_layer1 -> reuse its 8MB for h2 (4MB) + res (4MB)
  float* h2  = hpre;
  float* res = hpre + (size_t)NN*C2;

  hipMemsetAsync(rowbits, 0, (size_t)NN*NWORDS*4*2, stream);   // rowbits+colbits
  hipMemsetAsync(cnt, 0, (size_t)NN*4*2, stream);              // cnt+fill

  k_detect<<<1,256,0,stream>>>(ei32, mode);
  k_build<<<(EP+255)/256,256,0,stream>>>(ei32, mode, rowbits, colbits, cnt);
  k_scan<<<1,256,0,stream>>>(cnt, rowptr);
  k_fill<<<(EP+255)/256,256,0,stream>>>(ei32, mode, rowptr, fill, csr_src);
  k_deg<<<NN/4,256,0,stream>>>(rowbits, v1);
  k_mv<<<NN/4,256,0,stream>>>(rowbits, v1, v2);
  k_mv<<<NN/4,256,0,stream>>>(rowbits, v2, v3);
  k_motif<<<NN,64,0,stream>>>(rowbits, colbits, rowptr, csr_src, v3, mwc);

  k_gemm<<<dim3(C1/GBN, NN/GBM),256,0,stream>>>(x, W1, hpre, NN, C1, C1);
  k_attn1<<<NN,512,0,stream>>>(hpre, as1, ad1, asrc1, adst1);
  k_layer1<<<NN,128,0,stream>>>(rowptr, csr_src, mwc, asrc1, adst1, hpre, b1, h1);

  k_gemm<<<dim3(C2/GBN, NN/GBM),256,0,stream>>>(h1, W2, h2, NN, C2, C1);
  k_gemm<<<dim3(C2/GBN, NN/GBM),256,0,stream>>>(h1, resW2, res, NN, C2, C1);
  k_attn2<<<NN,64,0,stream>>>(h2, as2, ad2, asrc2, adst2);
  k_layer2<<<NN,64,0,stream>>>(rowptr, csr_src, mwc, asrc2, adst2, h2, res, b2, out);
}

// Round 6
// 267.720 us; speedup vs baseline: 1.6310x; 1.1757x over previous
//
#include <hip/hip_runtime.h>
#include <hip/hip_bf16.h>
#include <math.h>

#define NN 4096
#define EE 131072
#define EP (EE + NN)     // 135168 edges incl. self loops
#define C1 512
#define H1 8
#define C2 256
#define NWORDS 128       // 4096 bits / 32
#define KP 520           // padded K stride for bf16 split buffers (mult of 8)

typedef __attribute__((ext_vector_type(8))) short bf16x8;
typedef __attribute__((ext_vector_type(4))) float f32x4;

__device__ __forceinline__ float wredMaxf(float v){
#pragma unroll
  for(int o=32;o;o>>=1) v = fmaxf(v, __shfl_xor(v,o));
  return v;
}
__device__ __forceinline__ float wredSumf(float v){
#pragma unroll
  for(int o=32;o;o>>=1) v += __shfl_xor(v,o);
  return v;
}
__device__ __forceinline__ int wredSumi(int v){
#pragma unroll
  for(int o=32;o;o>>=1) v += __shfl_xor(v,o);
  return v;
}

__device__ __forceinline__ void bfsplit(float v, unsigned short& h, unsigned short& l){
  unsigned bits = __float_as_uint(v);
  h = (unsigned short)(bits>>16);
  float hf = __uint_as_float(bits & 0xFFFF0000u);
  float lo = v - hf;                       // exact
  l = (unsigned short)(__float_as_uint(lo)>>16);
}

// ---- edge dtype detection: int64 => high 32-bit words are all zero ----
__global__ __launch_bounds__(256) void k_detect(const int* __restrict__ ei32, int* __restrict__ mode){
  __shared__ int any;
  if(threadIdx.x==0) any = 0;
  __syncthreads();
  int nz = 0;
  for(int i=threadIdx.x;i<2048;i+=256) nz |= (ei32[2*i+1] != 0);
  if(nz) atomicOr(&any, 1);
  __syncthreads();
  if(threadIdx.x==0) *mode = any;   // 1 => int32, 0 => int64
}

__device__ __forceinline__ void edge_sd(const int* ei32, int mode, int e, int& s, int& d){
  if(e < EE){
    if(mode==0){ s = ei32[2*e]; d = ei32[2*(EE+e)]; }
    else       { s = ei32[e];   d = ei32[EE+e]; }
  } else { s = e - EE; d = s; }
}

__global__ __launch_bounds__(256) void k_build(const int* __restrict__ ei32, const int* __restrict__ mode,
    unsigned* __restrict__ rowbits, unsigned* __restrict__ colbits, unsigned* __restrict__ cnt){
  int e = blockIdx.x*256 + threadIdx.x;
  if(e >= EP) return;
  int m = *mode, s, d;
  edge_sd(ei32, m, e, s, d);
  atomicOr(&rowbits[s*NWORDS + (d>>5)], 1u<<(d&31));
  atomicOr(&colbits[d*NWORDS + (s>>5)], 1u<<(s&31));
  atomicAdd(&cnt[d], 1u);
}

__global__ __launch_bounds__(256) void k_scan(const unsigned* __restrict__ cnt, unsigned* __restrict__ rowptr){
  __shared__ unsigned part[256];
  int t = threadIdx.x;
  unsigned loc[16]; unsigned s = 0;
#pragma unroll
  for(int i=0;i<16;i++){ loc[i]=cnt[t*16+i]; s+=loc[i]; }
  part[t]=s; __syncthreads();
  for(int off=1;off<256;off<<=1){
    unsigned v = (t>=off)? part[t-off] : 0u;
    __syncthreads();
    part[t]+=v;
    __syncthreads();
  }
  unsigned run = (t==0)? 0u : part[t-1];
#pragma unroll
  for(int i=0;i<16;i++){ rowptr[t*16+i]=run; run+=loc[i]; }
  if(t==255) rowptr[NN]=run;
}

__global__ __launch_bounds__(256) void k_fill(const int* __restrict__ ei32, const int* __restrict__ mode,
    const unsigned* __restrict__ rowptr, unsigned* __restrict__ fill,
    unsigned* __restrict__ csr_src){
  int e = blockIdx.x*256 + threadIdx.x;
  if(e >= EP) return;
  int m = *mode, s, d;
  edge_sd(ei32, m, e, s, d);
  unsigned pos = rowptr[d] + atomicAdd(&fill[d], 1u);
  csr_src[pos]=(unsigned)s;
}

// v1 = A @ 1 (out-degree incl. self loop)
__global__ __launch_bounds__(256) void k_deg(const unsigned* __restrict__ rowbits, float* __restrict__ v1){
  int node = blockIdx.x*4 + (threadIdx.x>>6);
  int lane = threadIdx.x & 63;
  unsigned w0 = rowbits[node*NWORDS + 2*lane];
  unsigned w1 = rowbits[node*NWORDS + 2*lane + 1];
  int c = __popc(w0) + __popc(w1);
  c = wredSumi(c);
  if(lane==0) v1[node] = (float)c;
}

// vout = A @ vin
__global__ __launch_bounds__(256) void k_mv(const unsigned* __restrict__ rowbits,
    const float* __restrict__ vin, float* __restrict__ vout){
  int node = blockIdx.x*4 + (threadIdx.x>>6);
  int lane = threadIdx.x & 63;
  float sum = 0.f;
  unsigned w = rowbits[node*NWORDS + 2*lane]; int b0 = lane*64;
  while(w){ int b=__ffs(w)-1; sum += vin[b0+b]; w &= w-1; }
  w = rowbits[node*NWORDS + 2*lane + 1]; b0 = lane*64 + 32;
  while(w){ int b=__ffs(w)-1; sum += vin[b0+b]; w &= w-1; }
  sum = wredSumf(sum);
  if(lane==0) vout[node] = sum;
}

// per-dst: bit-plane counters g[k]=A^2[k,d] in REGISTERS (8 planes x 2 words/lane);
// per in-edge (s,d): A^3[s,d] = sum_p popc(rowbits[s] & plane_p) << p; mwc[base+i] = A3/max(rowsum3[s],1)
__global__ __launch_bounds__(64) void k_motif(const unsigned* __restrict__ rowbits, const unsigned* __restrict__ colbits,
    const unsigned* __restrict__ rowptr, const unsigned* __restrict__ csr_src,
    const float* __restrict__ v3, float* __restrict__ mwc){
  int d = blockIdx.x;
  int lane = threadIdx.x;
  __shared__ unsigned short nbr[1024];
  __shared__ int cntL;
  if(lane==0) cntL=0;
  __syncthreads();
  {
    unsigned w = colbits[d*NWORDS + 2*lane]; int b0 = lane*64;
    while(w){ int b=__ffs(w)-1; int pos=atomicAdd(&cntL,1); nbr[pos]=(unsigned short)(b0+b); w&=w-1; }
    w = colbits[d*NWORDS + 2*lane + 1]; b0 = lane*64 + 32;
    while(w){ int b=__ffs(w)-1; int pos=atomicAdd(&cntL,1); nbr[pos]=(unsigned short)(b0+b); w&=w-1; }
  }
  __syncthreads();
  int m = cntL;
  unsigned gp[8][2];
#pragma unroll
  for(int p=0;p<8;p++){ gp[p][0]=0u; gp[p][1]=0u; }
  for(int t0=0;t0<m;t0+=4){
    unsigned xa[4], xb[4];
#pragma unroll
    for(int j=0;j<4;j++){
      int tt=t0+j;
      if(tt<m){ int l = nbr[tt]; xa[j]=colbits[l*NWORDS+2*lane]; xb[j]=colbits[l*NWORDS+2*lane+1]; }
      else    { xa[j]=0u; xb[j]=0u; }
    }
#pragma unroll
    for(int j=0;j<4;j++){
      unsigned c = xa[j];
#pragma unroll
      for(int p=0;p<8;p++){ unsigned cy = gp[p][0] & c; gp[p][0] ^= c; c = cy; }
      c = xb[j];
#pragma unroll
      for(int p=0;p<8;p++){ unsigned cy = gp[p][1] & c; gp[p][1] ^= c; c = cy; }
    }
  }
  unsigned base = rowptr[d], deg = rowptr[d+1]-base;
  for(unsigned i0=0;i0<deg;i0+=4){
    unsigned sidx[4], ra[4], rb[4];
#pragma unroll
    for(int j=0;j<4;j++){
      unsigned ii = (i0+j < deg) ? (i0+j) : (deg-1);
      sidx[j] = csr_src[base+ii];
    }
#pragma unroll
    for(int j=0;j<4;j++){ ra[j]=rowbits[sidx[j]*NWORDS+2*lane]; rb[j]=rowbits[sidx[j]*NWORDS+2*lane+1]; }
    int sum[4];
#pragma unroll
    for(int j=0;j<4;j++){
      int s=0;
#pragma unroll
      for(int p=0;p<8;p++)
        s += (__popc(ra[j]&gp[p][0]) + __popc(rb[j]&gp[p][1])) << p;
      sum[j]=s;
    }
    int pk0 = sum[0] | (sum[1]<<16);
    int pk1 = sum[2] | (sum[3]<<16);
    pk0 = wredSumi(pk0); pk1 = wredSumi(pk1);
    if(lane==0){
      int ss[4] = { pk0 & 0xFFFF, (pk0>>16)&0xFFFF, pk1 & 0xFFFF, (pk1>>16)&0xFFFF };
#pragma unroll
      for(int j=0;j<4;j++){
        unsigned idx = i0+j;
        if(idx<deg)
          mwc[base+idx] = (float)ss[j] / fmaxf(v3[csr_src[base+idx]], 1.0f);
      }
    }
  }
}

// ---- x [4096][512] f32 -> hi/lo bf16 [4096][KP] ----
__global__ __launch_bounds__(256) void k_cvtA(const float* __restrict__ X,
    unsigned short* __restrict__ xh, unsigned short* __restrict__ xl){
  int e = blockIdx.x*256 + threadIdx.x;   // one thread = 8 elems
  int row = e >> 6;                       // 512/8 = 64 chunks per row
  int c0 = (e & 63) * 8;
  const float4 v0 = *(const float4*)&X[(size_t)row*C1 + c0];
  const float4 v1 = *(const float4*)&X[(size_t)row*C1 + c0 + 4];
  float vv[8] = {v0.x,v0.y,v0.z,v0.w,v1.x,v1.y,v1.z,v1.w};
  unsigned short h[8], l[8];
#pragma unroll
  for(int j=0;j<8;j++) bfsplit(vv[j], h[j], l[j]);
  *(bf16x8*)&xh[(size_t)row*KP + c0] = *(bf16x8*)h;
  *(bf16x8*)&xl[(size_t)row*KP + c0] = *(bf16x8*)l;
}

// ---- W [K=512][N] f32 -> transposed hi/lo bf16 [N][KP] ----
__global__ __launch_bounds__(256) void k_cvtB(const float* __restrict__ W, int N,
    unsigned short* __restrict__ bh, unsigned short* __restrict__ bl){
  int n = blockIdx.x; int t = threadIdx.x;
  int k = t*2;
  float a = W[(size_t)k*N + n];
  float b = W[(size_t)(k+1)*N + n];
  unsigned short h0,l0,h1,l1;
  bfsplit(a,h0,l0); bfsplit(b,h1,l1);
  unsigned short hp[2]={h0,h1}, lp[2]={l0,l1};
  *(unsigned int*)&bh[(size_t)n*KP + k] = *(unsigned int*)hp;
  *(unsigned int*)&bl[(size_t)n*KP + k] = *(unsigned int*)lp;
}

// ---- split-bf16 MFMA GEMM: C[M,N] = A @ B, K=512; A hi/lo [M][KP], B hi/lo [N][KP] (pre-transposed) ----
__global__ __launch_bounds__(256) void k_gemm_mfma(
    const unsigned short* __restrict__ Ah, const unsigned short* __restrict__ Al,
    const unsigned short* __restrict__ Bh, const unsigned short* __restrict__ Bl,
    float* __restrict__ C, int M, int N){
  __shared__ unsigned short Ahs[64][40], Als[64][40], Bhs[64][40], Bls[64][40];
  int bm = blockIdx.y*64, bn = blockIdx.x*64;
  int t = threadIdx.x, lane = t&63, w = t>>6;
  int wm = (w>>1)*32, wn = (w&1)*32;
  f32x4 acc[2][2];
#pragma unroll
  for(int i=0;i<2;i++)
#pragma unroll
    for(int j=0;j<2;j++) acc[i][j] = (f32x4){0.f,0.f,0.f,0.f};
  int sm = t>>2, skq = (t&3)*8;
  const unsigned short* pAh = &Ah[(size_t)(bm+sm)*KP + skq];
  const unsigned short* pAl = &Al[(size_t)(bm+sm)*KP + skq];
  const unsigned short* pBh = &Bh[(size_t)(bn+sm)*KP + skq];
  const unsigned short* pBl = &Bl[(size_t)(bn+sm)*KP + skq];
  int fr = lane&15, kg = lane>>4;
  for(int k0=0;k0<C1;k0+=32){
    *(bf16x8*)&Ahs[sm][skq] = *(const bf16x8*)(pAh + k0);
    *(bf16x8*)&Als[sm][skq] = *(const bf16x8*)(pAl + k0);
    *(bf16x8*)&Bhs[sm][skq] = *(const bf16x8*)(pBh + k0);
    *(bf16x8*)&Bls[sm][skq] = *(const bf16x8*)(pBl + k0);
    __syncthreads();
    bf16x8 ah[2], al[2], bh[2], bl[2];
#pragma unroll
    for(int i=0;i<2;i++){
      ah[i] = *(bf16x8*)&Ahs[wm + i*16 + fr][kg*8];
      al[i] = *(bf16x8*)&Als[wm + i*16 + fr][kg*8];
      bh[i] = *(bf16x8*)&Bhs[wn + i*16 + fr][kg*8];
      bl[i] = *(bf16x8*)&Bls[wn + i*16 + fr][kg*8];
    }
#pragma unroll
    for(int i=0;i<2;i++)
#pragma unroll
      for(int j=0;j<2;j++){
        acc[i][j] = __builtin_amdgcn_mfma_f32_16x16x32_bf16(ah[i], bh[j], acc[i][j], 0,0,0);
        acc[i][j] = __builtin_amdgcn_mfma_f32_16x16x32_bf16(ah[i], bl[j], acc[i][j], 0,0,0);
        acc[i][j] = __builtin_amdgcn_mfma_f32_16x16x32_bf16(al[i], bh[j], acc[i][j], 0,0,0);
      }
    __syncthreads();
  }
#pragma unroll
  for(int i=0;i<2;i++)
#pragma unroll
    for(int j=0;j<2;j++){
      int gr = bm + wm + i*16 + kg*4;
      int gc = bn + wn + j*16 + fr;
#pragma unroll
      for(int e=0;e<4;e++)
        C[(size_t)(gr+e)*N + gc] = acc[i][j][e];
    }
}

// per-node attention logit dots, layer 1 (8 heads x 64 ch)
__global__ __launch_bounds__(512) void k_attn1(const float* __restrict__ hpre, const float* __restrict__ as1,
    const float* __restrict__ ad1, float* __restrict__ asrc, float* __restrict__ adst){
  int n = blockIdx.x; int t = threadIdx.x; int lane = t&63; int h = t>>6;
  float v = hpre[n*C1 + t];
  float p1 = v*as1[t], p2 = v*ad1[t];
  p1 = wredSumf(p1); p2 = wredSumf(p2);
  if(lane==0){ asrc[n*H1+h]=p1; adst[n*H1+h]=p2; }
}

// layer-1: flash-style single-sweep dual segment-softmax + aggregation + bias + ELU
// emits h1 as bf16 hi/lo [NN][KP] for the downstream MFMA GEMM
__global__ __launch_bounds__(128) void k_layer1(const unsigned* __restrict__ rowptr, const unsigned* __restrict__ csr_src,
    const float* __restrict__ mwc, const float* __restrict__ asrc, const float* __restrict__ adst,
    const float* __restrict__ hpre, const float* __restrict__ b1,
    unsigned short* __restrict__ h1h, unsigned short* __restrict__ h1l){
  int n = blockIdx.x;
  int tid = threadIdx.x, lane = tid&63, wv = tid>>6;
  unsigned base = rowptr[n], deg = rowptr[n+1]-base;
  __shared__ float a1s[128][9];
  __shared__ float a2s[128][9];
  __shared__ unsigned ssrc[128];
  __shared__ float red1[2][8], red2[2][8];
  __shared__ float snm1[8], snm2[8], sscl1[8], sscl2[8];
  __shared__ float sS1[8], sS2[8], sM1[8], sM2[8];
  __shared__ float adsts[8];
  if(tid<8){ adsts[tid]=adst[n*H1+tid]; sM1[tid]=-3.0e38f; sM2[tid]=-3.0e38f; sS1[tid]=0.f; sS2[tid]=0.f; }
  __syncthreads();
  int h = tid>>4;
  float4 acc1={0.f,0.f,0.f,0.f}, acc2={0.f,0.f,0.f,0.f};
  for(unsigned c0=0;c0<deg;c0+=128){
    int csz = (int)min(128u, deg-c0);
    bool act = (tid < csz);
    float el[8], em[8];
    if(act){
      unsigned s = csr_src[base+c0+tid];
      ssrc[tid]=s;
      float mwv = mwc[base+c0+tid];
      const float4 a0v = *(const float4*)&asrc[s*H1];
      const float4 a1v = *(const float4*)&asrc[s*H1+4];
      float as8[8]={a0v.x,a0v.y,a0v.z,a0v.w,a1v.x,a1v.y,a1v.z,a1v.w};
#pragma unroll
      for(int hh=0;hh<8;hh++){
        float ev = as8[hh]+adsts[hh];
        el[hh] = ev>=0.f? ev : 0.2f*ev;
        float evm = ev*mwv;
        em[hh] = evm>=0.f? evm : 0.2f*evm;
      }
    } else {
#pragma unroll
      for(int hh=0;hh<8;hh++){ el[hh]=-3.0e38f; em[hh]=-3.0e38f; }
    }
    float mx1[8], mx2[8];
#pragma unroll
    for(int hh=0;hh<8;hh++){ mx1[hh]=wredMaxf(el[hh]); mx2[hh]=wredMaxf(em[hh]); }
    if(lane==0){
#pragma unroll
      for(int hh=0;hh<8;hh++){ red1[wv][hh]=mx1[hh]; red2[wv][hh]=mx2[hh]; }
    }
    __syncthreads();
    if(tid<8){
      float cm1 = fmaxf(red1[0][tid], red1[1][tid]);
      float cm2 = fmaxf(red2[0][tid], red2[1][tid]);
      float nm1 = fmaxf(sM1[tid], cm1), nm2 = fmaxf(sM2[tid], cm2);
      sscl1[tid] = expf(sM1[tid]-nm1); sscl2[tid] = expf(sM2[tid]-nm2);
      snm1[tid]=nm1; snm2[tid]=nm2;
      sM1[tid]=nm1;  sM2[tid]=nm2;
    }
    __syncthreads();
    float s1l[8], s2l[8];
#pragma unroll
    for(int hh=0;hh<8;hh++){
      float a1v = act? expf(el[hh]-snm1[hh]) : 0.f;
      float a2v = act? expf(em[hh]-snm2[hh]) : 0.f;
      if(act){ a1s[tid][hh]=a1v; a2s[tid][hh]=a2v; }
      s1l[hh]=a1v; s2l[hh]=a2v;
    }
#pragma unroll
    for(int hh=0;hh<8;hh++){ s1l[hh]=wredSumf(s1l[hh]); s2l[hh]=wredSumf(s2l[hh]); }
    if(lane==0){
#pragma unroll
      for(int hh=0;hh<8;hh++){ red1[wv][hh]=s1l[hh]; red2[wv][hh]=s2l[hh]; }
    }
    __syncthreads();
    if(tid<8){
      sS1[tid] = sS1[tid]*sscl1[tid] + red1[0][tid]+red1[1][tid];
      sS2[tid] = sS2[tid]*sscl2[tid] + red2[0][tid]+red2[1][tid];
    }
    {
      float sc1 = sscl1[h], sc2 = sscl2[h];
      acc1.x*=sc1; acc1.y*=sc1; acc1.z*=sc1; acc1.w*=sc1;
      acc2.x*=sc2; acc2.y*=sc2; acc2.z*=sc2; acc2.w*=sc2;
    }
    for(int i0=0;i0<csz;i0+=4){
      int jn = min(4, csz-i0);
      unsigned sj[4]; float a1j[4], a2j[4];
#pragma unroll
      for(int j=0;j<4;j++){
        int ii = (j<jn)? i0+j : i0;
        sj[j]=ssrc[ii]; a1j[j]=a1s[ii][h]; a2j[j]=a2s[ii][h];
      }
      float4 hv[4];
#pragma unroll
      for(int j=0;j<4;j++) hv[j] = *(const float4*)&hpre[(size_t)sj[j]*C1 + tid*4];
#pragma unroll
      for(int j=0;j<4;j++){
        float w1 = (j<jn)? a1j[j] : 0.f;
        float w2 = (j<jn)? a2j[j] : 0.f;
        acc1.x += w1*hv[j].x; acc1.y += w1*hv[j].y; acc1.z += w1*hv[j].z; acc1.w += w1*hv[j].w;
        acc2.x += w2*hv[j].x; acc2.y += w2*hv[j].y; acc2.z += w2*hv[j].z; acc2.w += w2*hv[j].w;
      }
    }
    __syncthreads();
  }
  float r1 = 0.5f/(sS1[h]+1e-16f), r2 = 0.5f/(sS2[h]+1e-16f);
  int cc = tid*4;
  const float4 bv = *(const float4*)&b1[cc];
  float o[4];
  float vx = acc1.x*r1 + acc2.x*r2 + bv.x; o[0] = vx>0.f? vx : expm1f(vx);
  float vy = acc1.y*r1 + acc2.y*r2 + bv.y; o[1] = vy>0.f? vy : expm1f(vy);
  float vz = acc1.z*r1 + acc2.z*r2 + bv.z; o[2] = vz>0.f? vz : expm1f(vz);
  float vw = acc1.w*r1 + acc2.w*r2 + bv.w; o[3] = vw>0.f? vw : expm1f(vw);
  unsigned short hh4[4], ll4[4];
#pragma unroll
  for(int j=0;j<4;j++) bfsplit(o[j], hh4[j], ll4[j]);
  *(ushort4*)&h1h[(size_t)n*KP + cc] = *(ushort4*)hh4;
  *(ushort4*)&h1l[(size_t)n*KP + cc] = *(ushort4*)ll4;
}

// per-node attention logit dots, layer 2 (1 head x 256 ch); h2 row stride 512 (cols 0..255 of C23)
__global__ __launch_bounds__(64) void k_attn2(const float* __restrict__ h2, const float* __restrict__ as2,
    const float* __restrict__ ad2, float* __restrict__ asrc, float* __restrict__ adst){
  int n = blockIdx.x; int lane = threadIdx.x;
  const float4 hv = *(const float4*)&h2[(size_t)n*512 + lane*4];
  const float4 av = *(const float4*)&as2[lane*4];
  const float4 dv = *(const float4*)&ad2[lane*4];
  float p1 = hv.x*av.x + hv.y*av.y + hv.z*av.z + hv.w*av.w;
  float p2 = hv.x*dv.x + hv.y*dv.y + hv.z*dv.z + hv.w*dv.w;
  p1 = wredSumf(p1); p2 = wredSumf(p2);
  if(lane==0){ asrc[n]=p1; adst[n]=p2; }
}

// layer-2: flash-style single-sweep + residual + bias -> d_out; h2/res row stride 512
__global__ __launch_bounds__(64) void k_layer2(const unsigned* __restrict__ rowptr, const unsigned* __restrict__ csr_src,
    const float* __restrict__ mwc, const float* __restrict__ asrc, const float* __restrict__ adst,
    const float* __restrict__ h2, const float* __restrict__ res,
    const float* __restrict__ b2, float* __restrict__ out){
  int n = blockIdx.x; int lane = threadIdx.x;
  unsigned base = rowptr[n], deg = rowptr[n+1]-base;
  __shared__ float a1s[64], a2s[64];
  __shared__ unsigned ssrc[64];
  float ad = adst[n];
  float M1=-3.0e38f, M2=-3.0e38f, S1=0.f, S2=0.f;
  float4 acc1={0.f,0.f,0.f,0.f}, acc2={0.f,0.f,0.f,0.f};
  for(unsigned c0=0;c0<deg;c0+=64){
    int csz = (int)min(64u, deg-c0);
    bool act = (lane < csz);
    float el=-3.0e38f, em=-3.0e38f;
    if(act){
      unsigned s = csr_src[base+c0+lane];
      ssrc[lane]=s;
      float mwv = mwc[base+c0+lane];
      float ev = asrc[s] + ad;
      el = ev>=0.f? ev : 0.2f*ev;
      float evm = ev*mwv;
      em = evm>=0.f? evm : 0.2f*evm;
    }
    float nm1 = fmaxf(M1, wredMaxf(el));
    float nm2 = fmaxf(M2, wredMaxf(em));
    float sc1 = expf(M1-nm1), sc2 = expf(M2-nm2);
    M1=nm1; M2=nm2;
    float a1 = act? expf(el-nm1) : 0.f;
    float a2 = act? expf(em-nm2) : 0.f;
    if(act){ a1s[lane]=a1; a2s[lane]=a2; }
    S1 = S1*sc1 + wredSumf(a1);
    S2 = S2*sc2 + wredSumf(a2);
    acc1.x*=sc1; acc1.y*=sc1; acc1.z*=sc1; acc1.w*=sc1;
    acc2.x*=sc2; acc2.y*=sc2; acc2.z*=sc2; acc2.w*=sc2;
    __syncthreads();
    for(int i0=0;i0<csz;i0+=4){
      int jn = min(4, csz-i0);
      unsigned sj[4]; float a1j[4], a2j[4];
#pragma unroll
      for(int j=0;j<4;j++){
        int ii = (j<jn)? i0+j : i0;
        sj[j]=ssrc[ii]; a1j[j]=a1s[ii]; a2j[j]=a2s[ii];
      }
      float4 hv[4];
#pragma unroll
      for(int j=0;j<4;j++) hv[j] = *(const float4*)&h2[(size_t)sj[j]*512 + lane*4];
#pragma unroll
      for(int j=0;j<4;j++){
        float w1 = (j<jn)? a1j[j] : 0.f;
        float w2 = (j<jn)? a2j[j] : 0.f;
        acc1.x += w1*hv[j].x; acc1.y += w1*hv[j].y; acc1.z += w1*hv[j].z; acc1.w += w1*hv[j].w;
        acc2.x += w2*hv[j].x; acc2.y += w2*hv[j].y; acc2.z += w2*hv[j].z; acc2.w += w2*hv[j].w;
      }
    }
    __syncthreads();
  }
  float r1 = 0.5f/(S1+1e-16f), r2 = 0.5f/(S2+1e-16f);
  int cc = lane*4;
  const float4 rv = *(const float4*)&res[(size_t)n*512 + cc];
  const float4 bv = *(const float4*)&b2[cc];
  float4 o = {acc1.x*r1 + acc2.x*r2 + rv.x + bv.x,
              acc1.y*r1 + acc2.y*r2 + rv.y + bv.y,
              acc1.z*r1 + acc2.z*r2 + rv.z + bv.z,
              acc1.w*r1 + acc2.w*r2 + rv.w + bv.w};
  *(float4*)&out[(size_t)n*C2 + cc] = o;
}

extern "C" void kernel_launch(void* const* d_in, const int* in_sizes, int n_in,
                              void* d_out, int out_size, void* d_ws, size_t ws_size,
                              hipStream_t stream) {
  const float* x    = (const float*)d_in[0];
  const int*   ei32 = (const int*)d_in[1];     // int64 vs int32 auto-detected
  const float* W1   = (const float*)d_in[2];
  const float* as1  = (const float*)d_in[3];
  const float* ad1  = (const float*)d_in[4];
  const float* b1   = (const float*)d_in[5];
  const float* W2   = (const float*)d_in[6];
  const float* as2  = (const float*)d_in[7];
  const float* ad2  = (const float*)d_in[8];
  const float* b2   = (const float*)d_in[9];
  const float* resW2= (const float*)d_in[10];
  float* out = (float*)d_out;

  char* p = (char*)d_ws;
  auto alloc = [&](size_t b){ void* r=(void*)p; p += (b + 255) & ~(size_t)255; return r; };
  unsigned* rowbits = (unsigned*)alloc((size_t)NN*NWORDS*4);   // 2MB
  unsigned* colbits = (unsigned*)alloc((size_t)NN*NWORDS*4);   // 2MB (contiguous with rowbits)
  unsigned* cnt     = (unsigned*)alloc(NN*4);
  unsigned* fill    = (unsigned*)alloc(NN*4);                  // contiguous with cnt
  unsigned* rowptr  = (unsigned*)alloc((NN+4)*4);
  float* v1 = (float*)alloc(NN*4);
  float* v2 = (float*)alloc(NN*4);
  float* v3 = (float*)alloc(NN*4);
  unsigned* csr_src = (unsigned*)alloc((size_t)EP*4);
  float* mwc  = (float*)alloc((size_t)EP*4);
  float* asrc1= (float*)alloc(NN*H1*4);
  float* adst1= (float*)alloc(NN*H1*4);
  unsigned short* xsh = (unsigned short*)alloc((size_t)NN*KP*2);  // 4.3MB
  unsigned short* xsl = (unsigned short*)alloc((size_t)NN*KP*2);
  unsigned short* bt1h= (unsigned short*)alloc((size_t)C1*KP*2);  // 0.5MB
  unsigned short* bt1l= (unsigned short*)alloc((size_t)C1*KP*2);
  unsigned short* bt2h= (unsigned short*)alloc((size_t)C1*KP*2);  // stacked W2|resW2 (N=512)
  unsigned short* bt2l= (unsigned short*)alloc((size_t)C1*KP*2);
  float* hpre = (float*)alloc((size_t)NN*C1*4);   // 8MB f32 (attn1 + layer1 gather)
  unsigned short* h1h = (unsigned short*)alloc((size_t)NN*KP*2);
  unsigned short* h1l = (unsigned short*)alloc((size_t)NN*KP*2);
  float* c23  = (float*)alloc((size_t)NN*512*4);  // 8MB: cols 0-255 = h2, 256-511 = res
  float* asrc2= (float*)alloc(NN*4);
  float* adst2= (float*)alloc(NN*4);
  int* mode   = (int*)alloc(256);
  float* h2  = c23;
  float* res = c23 + 256;

  hipMemsetAsync(rowbits, 0, (size_t)NN*NWORDS*4*2, stream);   // rowbits+colbits
  hipMemsetAsync(cnt, 0, (size_t)NN*4*2, stream);              // cnt+fill

  k_detect<<<1,256,0,stream>>>(ei32, mode);
  k_build<<<(EP+255)/256,256,0,stream>>>(ei32, mode, rowbits, colbits, cnt);
  k_scan<<<1,256,0,stream>>>(cnt, rowptr);
  k_fill<<<(EP+255)/256,256,0,stream>>>(ei32, mode, rowptr, fill, csr_src);
  k_deg<<<NN/4,256,0,stream>>>(rowbits, v1);
  k_mv<<<NN/4,256,0,stream>>>(rowbits, v1, v2);
  k_mv<<<NN/4,256,0,stream>>>(rowbits, v2, v3);
  k_motif<<<NN,64,0,stream>>>(rowbits, colbits, rowptr, csr_src, v3, mwc);

  k_cvtA<<<(NN*64)/256,256,0,stream>>>(x, xsh, xsl);
  k_cvtB<<<C1,256,0,stream>>>(W1, C1, bt1h, bt1l);
  k_cvtB<<<C2,256,0,stream>>>(W2, C2, bt2h, bt2l);
  k_cvtB<<<C2,256,0,stream>>>(resW2, C2, bt2h + (size_t)C2*KP, bt2l + (size_t)C2*KP);

  k_gemm_mfma<<<dim3(C1/64, NN/64),256,0,stream>>>(xsh, xsl, bt1h, bt1l, hpre, NN, C1);
  k_attn1<<<NN,512,0,stream>>>(hpre, as1, ad1, asrc1, adst1);
  k_layer1<<<NN,128,0,stream>>>(rowptr, csr_src, mwc, asrc1, adst1, hpre, b1, h1h, h1l);

  k_gemm_mfma<<<dim3(512/64, NN/64),256,0,stream>>>(h1h, h1l, bt2h, bt2l, c23, NN, 512);
  k_attn2<<<NN,64,0,stream>>>(h2, as2, ad2, asrc2, adst2);
  k_layer2<<<NN,64,0,stream>>>(rowptr, csr_src, mwc, asrc2, adst2, h2, res, b2, out);
}

// Round 7
// 253.564 us; speedup vs baseline: 1.7220x; 1.0558x over previous
//
#include <hip/hip_runtime.h>
#include <hip/hip_bf16.h>
#include <math.h>

#define NN 4096
#define EE 131072
#define EP (EE + NN)     // 135168 edges incl. self loops
#define C1 512
#define H1 8
#define C2 256
#define NWORDS 128       // 4096 bits / 32
#define KP 520           // padded K stride for bf16 split buffers (mult of 8)

typedef __attribute__((ext_vector_type(8))) short bf16x8;
typedef __attribute__((ext_vector_type(4))) float f32x4;

__device__ __forceinline__ float wredMaxf(float v){
#pragma unroll
  for(int o=32;o;o>>=1) v = fmaxf(v, __shfl_xor(v,o));
  return v;
}
__device__ __forceinline__ float wredSumf(float v){
#pragma unroll
  for(int o=32;o;o>>=1) v += __shfl_xor(v,o);
  return v;
}
__device__ __forceinline__ int wredSumi(int v){
#pragma unroll
  for(int o=32;o;o>>=1) v += __shfl_xor(v,o);
  return v;
}

__device__ __forceinline__ void bfsplit(float v, unsigned short& h, unsigned short& l){
  unsigned bits = __float_as_uint(v);
  h = (unsigned short)(bits>>16);
  float hf = __uint_as_float(bits & 0xFFFF0000u);
  float lo = v - hf;                       // exact
  l = (unsigned short)(__float_as_uint(lo)>>16);
}

// int64 edge_index => high words of first 8 entries are all zero.
// int32 => they are src[1],src[3],... (random 0..4095); all-zero prob ~(1/4096)^8.
__device__ __forceinline__ int detect_mode(const int* __restrict__ ei32){
  unsigned nz = 0;
#pragma unroll
  for(int i=1;i<16;i+=2) nz |= (unsigned)ei32[i];
  return nz != 0;   // 1 => int32, 0 => int64
}

__device__ __forceinline__ void edge_sd(const int* ei32, int mode, int e, int& s, int& d){
  if(e < EE){
    if(mode==0){ s = ei32[2*e]; d = ei32[2*(EE+e)]; }
    else       { s = ei32[e];   d = ei32[EE+e]; }
  } else { s = e - EE; d = s; }
}

__global__ __launch_bounds__(256) void k_build(const int* __restrict__ ei32,
    unsigned* __restrict__ rowbits, unsigned* __restrict__ colbits, unsigned* __restrict__ cnt){
  int e = blockIdx.x*256 + threadIdx.x;
  if(e >= EP) return;
  int m = detect_mode(ei32), s, d;
  edge_sd(ei32, m, e, s, d);
  atomicOr(&rowbits[s*NWORDS + (d>>5)], 1u<<(d&31));
  atomicOr(&colbits[d*NWORDS + (s>>5)], 1u<<(s&31));
  atomicAdd(&cnt[d], 1u);
}

__global__ __launch_bounds__(256) void k_scan(const unsigned* __restrict__ cnt, unsigned* __restrict__ rowptr){
  __shared__ unsigned part[256];
  int t = threadIdx.x;
  unsigned loc[16]; unsigned s = 0;
#pragma unroll
  for(int i=0;i<16;i++){ loc[i]=cnt[t*16+i]; s+=loc[i]; }
  part[t]=s; __syncthreads();
  for(int off=1;off<256;off<<=1){
    unsigned v = (t>=off)? part[t-off] : 0u;
    __syncthreads();
    part[t]+=v;
    __syncthreads();
  }
  unsigned run = (t==0)? 0u : part[t-1];
#pragma unroll
  for(int i=0;i<16;i++){ rowptr[t*16+i]=run; run+=loc[i]; }
  if(t==255) rowptr[NN]=run;
}

__global__ __launch_bounds__(256) void k_fill(const int* __restrict__ ei32,
    const unsigned* __restrict__ rowptr, unsigned* __restrict__ fill,
    unsigned* __restrict__ csr_src){
  int e = blockIdx.x*256 + threadIdx.x;
  if(e >= EP) return;
  int m = detect_mode(ei32), s, d;
  edge_sd(ei32, m, e, s, d);
  unsigned pos = rowptr[d] + atomicAdd(&fill[d], 1u);
  csr_src[pos]=(unsigned)s;
}

// v1 = A @ 1 (DISTINCT out-neighbors incl. self loop; dup edges collapse in adjacency)
__global__ __launch_bounds__(256) void k_deg(const unsigned* __restrict__ rowbits, float* __restrict__ v1){
  int node = blockIdx.x*4 + (threadIdx.x>>6);
  int lane = threadIdx.x & 63;
  unsigned w0 = rowbits[node*NWORDS + 2*lane];
  unsigned w1 = rowbits[node*NWORDS + 2*lane + 1];
  int c = __popc(w0) + __popc(w1);
  c = wredSumi(c);
  if(lane==0) v1[node] = (float)c;
}

// vout = A @ vin
__global__ __launch_bounds__(256) void k_mv(const unsigned* __restrict__ rowbits,
    const float* __restrict__ vin, float* __restrict__ vout){
  int node = blockIdx.x*4 + (threadIdx.x>>6);
  int lane = threadIdx.x & 63;
  float sum = 0.f;
  unsigned w = rowbits[node*NWORDS + 2*lane]; int b0 = lane*64;
  while(w){ int b=__ffs(w)-1; sum += vin[b0+b]; w &= w-1; }
  w = rowbits[node*NWORDS + 2*lane + 1]; b0 = lane*64 + 32;
  while(w){ int b=__ffs(w)-1; sum += vin[b0+b]; w &= w-1; }
  sum = wredSumf(sum);
  if(lane==0) vout[node] = sum;
}

// per-dst: bit-plane counters g[k]=A^2[k,d] in REGISTERS (8 planes x 2 words/lane);
// per in-edge (s,d): A^3[s,d] = sum_p popc(rowbits[s] & plane_p) << p; mwc[base+i] = A3/max(rowsum3[s],1)
__global__ __launch_bounds__(64) void k_motif(const unsigned* __restrict__ rowbits, const unsigned* __restrict__ colbits,
    const unsigned* __restrict__ rowptr, const unsigned* __restrict__ csr_src,
    const float* __restrict__ v3, float* __restrict__ mwc){
  int d = blockIdx.x;
  int lane = threadIdx.x;
  __shared__ unsigned short nbr[1024];
  __shared__ int cntL;
  if(lane==0) cntL=0;
  __syncthreads();
  {
    unsigned w = colbits[d*NWORDS + 2*lane]; int b0 = lane*64;
    while(w){ int b=__ffs(w)-1; int pos=atomicAdd(&cntL,1); nbr[pos]=(unsigned short)(b0+b); w&=w-1; }
    w = colbits[d*NWORDS + 2*lane + 1]; b0 = lane*64 + 32;
    while(w){ int b=__ffs(w)-1; int pos=atomicAdd(&cntL,1); nbr[pos]=(unsigned short)(b0+b); w&=w-1; }
  }
  __syncthreads();
  int m = cntL;
  unsigned gp[8][2];
#pragma unroll
  for(int p=0;p<8;p++){ gp[p][0]=0u; gp[p][1]=0u; }
  for(int t0=0;t0<m;t0+=4){
    unsigned xa[4], xb[4];
#pragma unroll
    for(int j=0;j<4;j++){
      int tt=t0+j;
      if(tt<m){ int l = nbr[tt]; xa[j]=colbits[l*NWORDS+2*lane]; xb[j]=colbits[l*NWORDS+2*lane+1]; }
      else    { xa[j]=0u; xb[j]=0u; }
    }
#pragma unroll
    for(int j=0;j<4;j++){
      unsigned c = xa[j];
#pragma unroll
      for(int p=0;p<8;p++){ unsigned cy = gp[p][0] & c; gp[p][0] ^= c; c = cy; }
      c = xb[j];
#pragma unroll
      for(int p=0;p<8;p++){ unsigned cy = gp[p][1] & c; gp[p][1] ^= c; c = cy; }
    }
  }
  unsigned base = rowptr[d], deg = rowptr[d+1]-base;
  for(unsigned i0=0;i0<deg;i0+=4){
    unsigned sidx[4], ra[4], rb[4];
#pragma unroll
    for(int j=0;j<4;j++){
      unsigned ii = (i0+j < deg) ? (i0+j) : (deg-1);
      sidx[j] = csr_src[base+ii];
    }
#pragma unroll
    for(int j=0;j<4;j++){ ra[j]=rowbits[sidx[j]*NWORDS+2*lane]; rb[j]=rowbits[sidx[j]*NWORDS+2*lane+1]; }
    int sum[4];
#pragma unroll
    for(int j=0;j<4;j++){
      int s=0;
#pragma unroll
      for(int p=0;p<8;p++)
        s += (__popc(ra[j]&gp[p][0]) + __popc(rb[j]&gp[p][1])) << p;
      sum[j]=s;
    }
    int pk0 = sum[0] | (sum[1]<<16);
    int pk1 = sum[2] | (sum[3]<<16);
    pk0 = wredSumi(pk0); pk1 = wredSumi(pk1);
    if(lane==0){
      int ss[4] = { pk0 & 0xFFFF, (pk0>>16)&0xFFFF, pk1 & 0xFFFF, (pk1>>16)&0xFFFF };
#pragma unroll
      for(int j=0;j<4;j++){
        unsigned idx = i0+j;
        if(idx<deg)
          mwc[base+idx] = (float)ss[j] / fmaxf(v3[csr_src[base+idx]], 1.0f);
      }
    }
  }
}

// ---- x [4096][512] f32 -> hi/lo bf16 [4096][KP] ----
__global__ __launch_bounds__(256) void k_cvtA(const float* __restrict__ X,
    unsigned short* __restrict__ xh, unsigned short* __restrict__ xl){
  int e = blockIdx.x*256 + threadIdx.x;   // one thread = 8 elems
  int row = e >> 6;                       // 512/8 = 64 chunks per row
  int c0 = (e & 63) * 8;
  const float4 v0 = *(const float4*)&X[(size_t)row*C1 + c0];
  const float4 v1 = *(const float4*)&X[(size_t)row*C1 + c0 + 4];
  float vv[8] = {v0.x,v0.y,v0.z,v0.w,v1.x,v1.y,v1.z,v1.w};
  unsigned short h[8], l[8];
#pragma unroll
  for(int j=0;j<8;j++) bfsplit(vv[j], h[j], l[j]);
  *(bf16x8*)&xh[(size_t)row*KP + c0] = *(bf16x8*)h;
  *(bf16x8*)&xl[(size_t)row*KP + c0] = *(bf16x8*)l;
}

// ---- fused weight convert/transpose: W1 (512x512), W2 (512x256), resW2 (512x256) ----
// blocks 0..511 -> W1 col n; 512..767 -> W2 col n-512; 768..1023 -> resW2 col n-768 (stacked rows 256..511)
__global__ __launch_bounds__(256) void k_cvtB_all(const float* __restrict__ W1f,
    const float* __restrict__ W2f, const float* __restrict__ Wrf,
    unsigned short* __restrict__ b1h, unsigned short* __restrict__ b1l,
    unsigned short* __restrict__ b2h, unsigned short* __restrict__ b2l){
  int blk = blockIdx.x; int t = threadIdx.x;
  const float* W; int N, n, nrow; unsigned short *bh, *bl;
  if(blk < 512){ W=W1f; N=512; n=blk;     nrow=n;     bh=b1h; bl=b1l; }
  else if(blk < 768){ W=W2f; N=256; n=blk-512; nrow=n;     bh=b2h; bl=b2l; }
  else { W=Wrf; N=256; n=blk-768; nrow=n+256; bh=b2h; bl=b2l; }
  int k = t*2;
  float a = W[(size_t)k*N + n];
  float b = W[(size_t)(k+1)*N + n];
  unsigned short h0,l0,h1,l1;
  bfsplit(a,h0,l0); bfsplit(b,h1,l1);
  unsigned short hp[2]={h0,h1}, lp[2]={l0,l1};
  *(unsigned int*)&bh[(size_t)nrow*KP + k] = *(unsigned int*)hp;
  *(unsigned int*)&bl[(size_t)nrow*KP + k] = *(unsigned int*)lp;
}

// ---- split-bf16 MFMA GEMM: C[M,N] = A @ B, K=512; BK=64, reg-prefetch pipeline ----
__global__ __launch_bounds__(256) void k_gemm_mfma(
    const unsigned short* __restrict__ Ah, const unsigned short* __restrict__ Al,
    const unsigned short* __restrict__ Bh, const unsigned short* __restrict__ Bl,
    float* __restrict__ C, int M, int N){
  __shared__ unsigned short Ahs[64][72], Als[64][72], Bhs[64][72], Bls[64][72];
  int bm = blockIdx.y*64, bn = blockIdx.x*64;
  int t = threadIdx.x, lane = t&63, w = t>>6;
  int wm = (w>>1)*32, wn = (w&1)*32;
  f32x4 acc[2][2];
#pragma unroll
  for(int i=0;i<2;i++)
#pragma unroll
    for(int j=0;j<2;j++) acc[i][j] = (f32x4){0.f,0.f,0.f,0.f};
  int sm = t>>2, sk = (t&3)*16;           // each thread stages 16 shorts (2x16B) per matrix
  const unsigned short* pAh = &Ah[(size_t)(bm+sm)*KP + sk];
  const unsigned short* pAl = &Al[(size_t)(bm+sm)*KP + sk];
  const unsigned short* pBh = &Bh[(size_t)(bn+sm)*KP + sk];
  const unsigned short* pBl = &Bl[(size_t)(bn+sm)*KP + sk];
  int fr = lane&15, kg = lane>>4;
  // prologue: stage k0=0
  bf16x8 rah0 = *(const bf16x8*)(pAh), rah1 = *(const bf16x8*)(pAh+8);
  bf16x8 ral0 = *(const bf16x8*)(pAl), ral1 = *(const bf16x8*)(pAl+8);
  bf16x8 rbh0 = *(const bf16x8*)(pBh), rbh1 = *(const bf16x8*)(pBh+8);
  bf16x8 rbl0 = *(const bf16x8*)(pBl), rbl1 = *(const bf16x8*)(pBl+8);
  *(bf16x8*)&Ahs[sm][sk] = rah0; *(bf16x8*)&Ahs[sm][sk+8] = rah1;
  *(bf16x8*)&Als[sm][sk] = ral0; *(bf16x8*)&Als[sm][sk+8] = ral1;
  *(bf16x8*)&Bhs[sm][sk] = rbh0; *(bf16x8*)&Bhs[sm][sk+8] = rbh1;
  *(bf16x8*)&Bls[sm][sk] = rbl0; *(bf16x8*)&Bls[sm][sk+8] = rbl1;
  __syncthreads();
  for(int k0=0;k0<C1;k0+=64){
    int kn = k0+64;
    if(kn<C1){   // prefetch next K-tile into regs (hides HBM under MFMA)
      rah0 = *(const bf16x8*)(pAh+kn); rah1 = *(const bf16x8*)(pAh+kn+8);
      ral0 = *(const bf16x8*)(pAl+kn); ral1 = *(const bf16x8*)(pAl+kn+8);
      rbh0 = *(const bf16x8*)(pBh+kn); rbh1 = *(const bf16x8*)(pBh+kn+8);
      rbl0 = *(const bf16x8*)(pBl+kn); rbl1 = *(const bf16x8*)(pBl+kn+8);
    }
#pragma unroll
    for(int ks=0;ks<64;ks+=32){
      bf16x8 fah[2], fal[2], fbh[2], fbl[2];
#pragma unroll
      for(int i=0;i<2;i++){
        fah[i] = *(bf16x8*)&Ahs[wm + i*16 + fr][ks + kg*8];
        fal[i] = *(bf16x8*)&Als[wm + i*16 + fr][ks + kg*8];
        fbh[i] = *(bf16x8*)&Bhs[wn + i*16 + fr][ks + kg*8];
        fbl[i] = *(bf16x8*)&Bls[wn + i*16 + fr][ks + kg*8];
      }
#pragma unroll
      for(int i=0;i<2;i++)
#pragma unroll
        for(int j=0;j<2;j++){
          acc[i][j] = __builtin_amdgcn_mfma_f32_16x16x32_bf16(fah[i], fbh[j], acc[i][j], 0,0,0);
          acc[i][j] = __builtin_amdgcn_mfma_f32_16x16x32_bf16(fah[i], fbl[j], acc[i][j], 0,0,0);
          acc[i][j] = __builtin_amdgcn_mfma_f32_16x16x32_bf16(fal[i], fbh[j], acc[i][j], 0,0,0);
        }
    }
    __syncthreads();
    if(kn<C1){
      *(bf16x8*)&Ahs[sm][sk] = rah0; *(bf16x8*)&Ahs[sm][sk+8] = rah1;
      *(bf16x8*)&Als[sm][sk] = ral0; *(bf16x8*)&Als[sm][sk+8] = ral1;
      *(bf16x8*)&Bhs[sm][sk] = rbh0; *(bf16x8*)&Bhs[sm][sk+8] = rbh1;
      *(bf16x8*)&Bls[sm][sk] = rbl0; *(bf16x8*)&Bls[sm][sk+8] = rbl1;
    }
    __syncthreads();
  }
#pragma unroll
  for(int i=0;i<2;i++)
#pragma unroll
    for(int j=0;j<2;j++){
      int gr = bm + wm + i*16 + kg*4;
      int gc = bn + wn + j*16 + fr;
#pragma unroll
      for(int e=0;e<4;e++)
        C[(size_t)(gr+e)*N + gc] = acc[i][j][e];
    }
}

// per-node attention logit dots, layer 1 (8 heads x 64 ch)
__global__ __launch_bounds__(512) void k_attn1(const float* __restrict__ hpre, const float* __restrict__ as1,
    const float* __restrict__ ad1, float* __restrict__ asrc, float* __restrict__ adst){
  int n = blockIdx.x; int t = threadIdx.x; int lane = t&63; int h = t>>6;
  float v = hpre[n*C1 + t];
  float p1 = v*as1[t], p2 = v*ad1[t];
  p1 = wredSumf(p1); p2 = wredSumf(p2);
  if(lane==0){ asrc[n*H1+h]=p1; adst[n*H1+h]=p2; }
}

// layer-1: flash-style single-sweep dual segment-softmax + aggregation + bias + ELU
// emits h1 as bf16 hi/lo [NN][KP] for the downstream MFMA GEMM
__global__ __launch_bounds__(128) void k_layer1(const unsigned* __restrict__ rowptr, const unsigned* __restrict__ csr_src,
    const float* __restrict__ mwc, const float* __restrict__ asrc, const float* __restrict__ adst,
    const float* __restrict__ hpre, const float* __restrict__ b1,
    unsigned short* __restrict__ h1h, unsigned short* __restrict__ h1l){
  int n = blockIdx.x;
  int tid = threadIdx.x, lane = tid&63, wv = tid>>6;
  unsigned base = rowptr[n], deg = rowptr[n+1]-base;
  __shared__ float a1s[128][9];
  __shared__ float a2s[128][9];
  __shared__ unsigned ssrc[128];
  __shared__ float red1[2][8], red2[2][8];
  __shared__ float snm1[8], snm2[8], sscl1[8], sscl2[8];
  __shared__ float sS1[8], sS2[8], sM1[8], sM2[8];
  __shared__ float adsts[8];
  if(tid<8){ adsts[tid]=adst[n*H1+tid]; sM1[tid]=-3.0e38f; sM2[tid]=-3.0e38f; sS1[tid]=0.f; sS2[tid]=0.f; }
  __syncthreads();
  int h = tid>>4;
  float4 acc1={0.f,0.f,0.f,0.f}, acc2={0.f,0.f,0.f,0.f};
  for(unsigned c0=0;c0<deg;c0+=128){
    int csz = (int)min(128u, deg-c0);
    bool act = (tid < csz);
    float el[8], em[8];
    if(act){
      unsigned s = csr_src[base+c0+tid];
      ssrc[tid]=s;
      float mwv = mwc[base+c0+tid];
      const float4 a0v = *(const float4*)&asrc[s*H1];
      const float4 a1v = *(const float4*)&asrc[s*H1+4];
      float as8[8]={a0v.x,a0v.y,a0v.z,a0v.w,a1v.x,a1v.y,a1v.z,a1v.w};
#pragma unroll
      for(int hh=0;hh<8;hh++){
        float ev = as8[hh]+adsts[hh];
        el[hh] = ev>=0.f? ev : 0.2f*ev;
        float evm = ev*mwv;
        em[hh] = evm>=0.f? evm : 0.2f*evm;
      }
    } else {
#pragma unroll
      for(int hh=0;hh<8;hh++){ el[hh]=-3.0e38f; em[hh]=-3.0e38f; }
    }
    float mx1[8], mx2[8];
#pragma unroll
    for(int hh=0;hh<8;hh++){ mx1[hh]=wredMaxf(el[hh]); mx2[hh]=wredMaxf(em[hh]); }
    if(lane==0){
#pragma unroll
      for(int hh=0;hh<8;hh++){ red1[wv][hh]=mx1[hh]; red2[wv][hh]=mx2[hh]; }
    }
    __syncthreads();
    if(tid<8){
      float cm1 = fmaxf(red1[0][tid], red1[1][tid]);
      float cm2 = fmaxf(red2[0][tid], red2[1][tid]);
      float nm1 = fmaxf(sM1[tid], cm1), nm2 = fmaxf(sM2[tid], cm2);
      sscl1[tid] = expf(sM1[tid]-nm1); sscl2[tid] = expf(sM2[tid]-nm2);
      snm1[tid]=nm1; snm2[tid]=nm2;
      sM1[tid]=nm1;  sM2[tid]=nm2;
    }
    __syncthreads();
    float s1l[8], s2l[8];
#pragma unroll
    for(int hh=0;hh<8;hh++){
      float a1v = act? expf(el[hh]-snm1[hh]) : 0.f;
      float a2v = act? expf(em[hh]-snm2[hh]) : 0.f;
      if(act){ a1s[tid][hh]=a1v; a2s[tid][hh]=a2v; }
      s1l[hh]=a1v; s2l[hh]=a2v;
    }
#pragma unroll
    for(int hh=0;hh<8;hh++){ s1l[hh]=wredSumf(s1l[hh]); s2l[hh]=wredSumf(s2l[hh]); }
    if(lane==0){
#pragma unroll
      for(int hh=0;hh<8;hh++){ red1[wv][hh]=s1l[hh]; red2[wv][hh]=s2l[hh]; }
    }
    __syncthreads();
    if(tid<8){
      sS1[tid] = sS1[tid]*sscl1[tid] + red1[0][tid]+red1[1][tid];
      sS2[tid] = sS2[tid]*sscl2[tid] + red2[0][tid]+red2[1][tid];
    }
    {
      float sc1 = sscl1[h], sc2 = sscl2[h];
      acc1.x*=sc1; acc1.y*=sc1; acc1.z*=sc1; acc1.w*=sc1;
      acc2.x*=sc2; acc2.y*=sc2; acc2.z*=sc2; acc2.w*=sc2;
    }
    // 8-edge batched gathers (thread owns channels tid*4..tid*4+3)
    for(int i0=0;i0<csz;i0+=8){
      int jn = min(8, csz-i0);
      unsigned sj[8]; float a1j[8], a2j[8];
#pragma unroll
      for(int j=0;j<8;j++){
        int ii = (j<jn)? i0+j : i0;
        sj[j]=ssrc[ii]; a1j[j]=a1s[ii][h]; a2j[j]=a2s[ii][h];
      }
      float4 hv[8];
#pragma unroll
      for(int j=0;j<8;j++) hv[j] = *(const float4*)&hpre[(size_t)sj[j]*C1 + tid*4];
#pragma unroll
      for(int j=0;j<8;j++){
        float w1 = (j<jn)? a1j[j] : 0.f;
        float w2 = (j<jn)? a2j[j] : 0.f;
        acc1.x += w1*hv[j].x; acc1.y += w1*hv[j].y; acc1.z += w1*hv[j].z; acc1.w += w1*hv[j].w;
        acc2.x += w2*hv[j].x; acc2.y += w2*hv[j].y; acc2.z += w2*hv[j].z; acc2.w += w2*hv[j].w;
      }
    }
    __syncthreads();
  }
  float r1 = 0.5f/(sS1[h]+1e-16f), r2 = 0.5f/(sS2[h]+1e-16f);
  int cc = tid*4;
  const float4 bv = *(const float4*)&b1[cc];
  float o[4];
  float vx = acc1.x*r1 + acc2.x*r2 + bv.x; o[0] = vx>0.f? vx : expm1f(vx);
  float vy = acc1.y*r1 + acc2.y*r2 + bv.y; o[1] = vy>0.f? vy : expm1f(vy);
  float vz = acc1.z*r1 + acc2.z*r2 + bv.z; o[2] = vz>0.f? vz : expm1f(vz);
  float vw = acc1.w*r1 + acc2.w*r2 + bv.w; o[3] = vw>0.f? vw : expm1f(vw);
  unsigned short hh4[4], ll4[4];
#pragma unroll
  for(int j=0;j<4;j++) bfsplit(o[j], hh4[j], ll4[j]);
  *(ushort4*)&h1h[(size_t)n*KP + cc] = *(ushort4*)hh4;
  *(ushort4*)&h1l[(size_t)n*KP + cc] = *(ushort4*)ll4;
}

// per-node attention logit dots, layer 2 (1 head x 256 ch); h2 row stride 512 (cols 0..255 of C23)
__global__ __launch_bounds__(64) void k_attn2(const float* __restrict__ h2, const float* __restrict__ as2,
    const float* __restrict__ ad2, float* __restrict__ asrc, float* __restrict__ adst){
  int n = blockIdx.x; int lane = threadIdx.x;
  const float4 hv = *(const float4*)&h2[(size_t)n*512 + lane*4];
  const float4 av = *(const float4*)&as2[lane*4];
  const float4 dv = *(const float4*)&ad2[lane*4];
  float p1 = hv.x*av.x + hv.y*av.y + hv.z*av.z + hv.w*av.w;
  float p2 = hv.x*dv.x + hv.y*dv.y + hv.z*dv.z + hv.w*dv.w;
  p1 = wredSumf(p1); p2 = wredSumf(p2);
  if(lane==0){ asrc[n]=p1; adst[n]=p2; }
}

// layer-2: flash-style single-sweep + residual + bias -> d_out; h2/res row stride 512
__global__ __launch_bounds__(64) void k_layer2(const unsigned* __restrict__ rowptr, const unsigned* __restrict__ csr_src,
    const float* __restrict__ mwc, const float* __restrict__ asrc, const float* __restrict__ adst,
    const float* __restrict__ h2, const float* __restrict__ res,
    const float* __restrict__ b2, float* __restrict__ out){
  int n = blockIdx.x; int lane = threadIdx.x;
  unsigned base = rowptr[n], deg = rowptr[n+1]-base;
  __shared__ float a1s[64], a2s[64];
  __shared__ unsigned ssrc[64];
  float ad = adst[n];
  float M1=-3.0e38f, M2=-3.0e38f, S1=0.f, S2=0.f;
  float4 acc1={0.f,0.f,0.f,0.f}, acc2={0.f,0.f,0.f,0.f};
  for(unsigned c0=0;c0<deg;c0+=64){
    int csz = (int)min(64u, deg-c0);
    bool act = (lane < csz);
    float el=-3.0e38f, em=-3.0e38f;
    if(act){
      unsigned s = csr_src[base+c0+lane];
      ssrc[lane]=s;
      float mwv = mwc[base+c0+lane];
      float ev = asrc[s] + ad;
      el = ev>=0.f? ev : 0.2f*ev;
      float evm = ev*mwv;
      em = evm>=0.f? evm : 0.2f*evm;
    }
    float nm1 = fmaxf(M1, wredMaxf(el));
    float nm2 = fmaxf(M2, wredMaxf(em));
    float sc1 = expf(M1-nm1), sc2 = expf(M2-nm2);
    M1=nm1; M2=nm2;
    float a1 = act? expf(el-nm1) : 0.f;
    float a2 = act? expf(em-nm2) : 0.f;
    if(act){ a1s[lane]=a1; a2s[lane]=a2; }
    S1 = S1*sc1 + wredSumf(a1);
    S2 = S2*sc2 + wredSumf(a2);
    acc1.x*=sc1; acc1.y*=sc1; acc1.z*=sc1; acc1.w*=sc1;
    acc2.x*=sc2; acc2.y*=sc2; acc2.z*=sc2; acc2.w*=sc2;
    __syncthreads();
    for(int i0=0;i0<csz;i0+=8){
      int jn = min(8, csz-i0);
      unsigned sj[8]; float a1j[8], a2j[8];
#pragma unroll
      for(int j=0;j<8;j++){
        int ii = (j<jn)? i0+j : i0;
        sj[j]=ssrc[ii]; a1j[j]=a1s[ii]; a2j[j]=a2s[ii];
      }
      float4 hv[8];
#pragma unroll
      for(int j=0;j<8;j++) hv[j] = *(const float4*)&h2[(size_t)sj[j]*512 + lane*4];
#pragma unroll
      for(int j=0;j<8;j++){
        float w1 = (j<jn)? a1j[j] : 0.f;
        float w2 = (j<jn)? a2j[j] : 0.f;
        acc1.x += w1*hv[j].x; acc1.y += w1*hv[j].y; acc1.z += w1*hv[j].z; acc1.w += w1*hv[j].w;
        acc2.x += w2*hv[j].x; acc2.y += w2*hv[j].y; acc2.z += w2*hv[j].z; acc2.w += w2*hv[j].w;
      }
    }
    __syncthreads();
  }
  float r1 = 0.5f/(S1+1e-16f), r2 = 0.5f/(S2+1e-16f);
  int cc = lane*4;
  const float4 rv = *(const float4*)&res[(size_t)n*512 + cc];
  const float4 bv = *(const float4*)&b2[cc];
  float4 o = {acc1.x*r1 + acc2.x*r2 + rv.x + bv.x,
              acc1.y*r1 + acc2.y*r2 + rv.y + bv.y,
              acc1.z*r1 + acc2.z*r2 + rv.z + bv.z,
              acc1.w*r1 + acc2.w*r2 + rv.w + bv.w};
  *(float4*)&out[(size_t)n*C2 + cc] = o;
}

extern "C" void kernel_launch(void* const* d_in, const int* in_sizes, int n_in,
                              void* d_out, int out_size, void* d_ws, size_t ws_size,
                              hipStream_t stream) {
  const float* x    = (const float*)d_in[0];
  const int*   ei32 = (const int*)d_in[1];     // int64 vs int32 detected inline per-kernel
  const float* W1   = (const float*)d_in[2];
  const float* as1  = (const float*)d_in[3];
  const float* ad1  = (const float*)d_in[4];
  const float* b1   = (const float*)d_in[5];
  const float* W2   = (const float*)d_in[6];
  const float* as2  = (const float*)d_in[7];
  const float* ad2  = (const float*)d_in[8];
  const float* b2   = (const float*)d_in[9];
  const float* resW2= (const float*)d_in[10];
  float* out = (float*)d_out;

  char* p = (char*)d_ws;
  auto alloc = [&](size_t b){ void* r=(void*)p; p += (b + 255) & ~(size_t)255; return r; };
  // zero-init region (one memset): rowbits, colbits, cnt, fill — contiguous
  unsigned* rowbits = (unsigned*)alloc((size_t)NN*NWORDS*4);   // 2MB
  unsigned* colbits = (unsigned*)alloc((size_t)NN*NWORDS*4);   // 2MB
  unsigned* cnt     = (unsigned*)alloc(NN*4);                  // 16KB
  unsigned* fill    = (unsigned*)alloc(NN*4);                  // 16KB
  size_t zbytes = (size_t)NN*NWORDS*4*2 + (size_t)NN*4*2;
  unsigned* rowptr  = (unsigned*)alloc((NN+4)*4);
  float* v1 = (float*)alloc(NN*4);
  float* v2 = (float*)alloc(NN*4);
  float* v3 = (float*)alloc(NN*4);
  unsigned* csr_src = (unsigned*)alloc((size_t)EP*4);
  float* mwc  = (float*)alloc((size_t)EP*4);
  float* asrc1= (float*)alloc(NN*H1*4);
  float* adst1= (float*)alloc(NN*H1*4);
  unsigned short* xsh = (unsigned short*)alloc((size_t)NN*KP*2);  // 4.3MB
  unsigned short* xsl = (unsigned short*)alloc((size_t)NN*KP*2);
  unsigned short* bt1h= (unsigned short*)alloc((size_t)C1*KP*2);
  unsigned short* bt1l= (unsigned short*)alloc((size_t)C1*KP*2);
  unsigned short* bt2h= (unsigned short*)alloc((size_t)C1*KP*2);  // stacked W2|resW2 (N=512)
  unsigned short* bt2l= (unsigned short*)alloc((size_t)C1*KP*2);
  float* hpre = (float*)alloc((size_t)NN*C1*4);   // 8MB f32 (attn1 + layer1 gather)
  unsigned short* h1h = (unsigned short*)alloc((size_t)NN*KP*2);
  unsigned short* h1l = (unsigned short*)alloc((size_t)NN*KP*2);
  float* c23  = (float*)alloc((size_t)NN*512*4);  // 8MB: cols 0-255 = h2, 256-511 = res
  float* asrc2= (float*)alloc(NN*4);
  float* adst2= (float*)alloc(NN*4);
  float* h2  = c23;
  float* res = c23 + 256;

  hipMemsetAsync(rowbits, 0, zbytes, stream);

  k_build<<<(EP+255)/256,256,0,stream>>>(ei32, rowbits, colbits, cnt);
  k_scan<<<1,256,0,stream>>>(cnt, rowptr);
  k_fill<<<(EP+255)/256,256,0,stream>>>(ei32, rowptr, fill, csr_src);
  k_deg<<<NN/4,256,0,stream>>>(rowbits, v1);
  k_mv<<<NN/4,256,0,stream>>>(rowbits, v1, v2);
  k_mv<<<NN/4,256,0,stream>>>(rowbits, v2, v3);
  k_motif<<<NN,64,0,stream>>>(rowbits, colbits, rowptr, csr_src, v3, mwc);

  k_cvtA<<<(NN*64)/256,256,0,stream>>>(x, xsh, xsl);
  k_cvtB_all<<<1024,256,0,stream>>>(W1, W2, resW2, bt1h, bt1l, bt2h, bt2l);

  k_gemm_mfma<<<dim3(C1/64, NN/64),256,0,stream>>>(xsh, xsl, bt1h, bt1l, hpre, NN, C1);
  k_attn1<<<NN,512,0,stream>>>(hpre, as1, ad1, asrc1, adst1);
  k_layer1<<<NN,128,0,stream>>>(rowptr, csr_src, mwc, asrc1, adst1, hpre, b1, h1h, h1l);

  k_gemm_mfma<<<dim3(512/64, NN/64),256,0,stream>>>(h1h, h1l, bt2h, bt2l, c23, NN, 512);
  k_attn2<<<NN,64,0,stream>>>(h2, as2, ad2, asrc2, adst2);
  k_layer2<<<NN,64,0,stream>>>(rowptr, csr_src, mwc, asrc2, adst2, h2, res, b2, out);
}

// Round 8
// 250.854 us; speedup vs baseline: 1.7406x; 1.0108x over previous
//
#include <hip/hip_runtime.h>
#include <hip/hip_bf16.h>
#include <math.h>

#define NN 4096
#define EE 131072
#define EP (EE + NN)     // 135168 edges incl. self loops
#define C1 512
#define H1 8
#define C2 256
#define NWORDS 128       // 4096 bits / 32
#define KP 520           // padded K stride for bf16 split buffers (mult of 8)

typedef __attribute__((ext_vector_type(8))) short bf16x8;
typedef __attribute__((ext_vector_type(4))) float f32x4;

__device__ __forceinline__ float wredMaxf(float v){
#pragma unroll
  for(int o=32;o;o>>=1) v = fmaxf(v, __shfl_xor(v,o));
  return v;
}
__device__ __forceinline__ float wredSumf(float v){
#pragma unroll
  for(int o=32;o;o>>=1) v += __shfl_xor(v,o);
  return v;
}
__device__ __forceinline__ int wredSumi(int v){
#pragma unroll
  for(int o=32;o;o>>=1) v += __shfl_xor(v,o);
  return v;
}

__device__ __forceinline__ void bfsplit(float v, unsigned short& h, unsigned short& l){
  unsigned bits = __float_as_uint(v);
  h = (unsigned short)(bits>>16);
  float hf = __uint_as_float(bits & 0xFFFF0000u);
  float lo = v - hf;                       // exact
  l = (unsigned short)(__float_as_uint(lo)>>16);
}

// int64 edge_index => high words of first 8 entries are all zero.
__device__ __forceinline__ int detect_mode(const int* __restrict__ ei32){
  unsigned nz = 0;
#pragma unroll
  for(int i=1;i<16;i+=2) nz |= (unsigned)ei32[i];
  return nz != 0;   // 1 => int32, 0 => int64
}

__device__ __forceinline__ void edge_sd(const int* ei32, int mode, int e, int& s, int& d){
  if(e < EE){
    if(mode==0){ s = ei32[2*e]; d = ei32[2*(EE+e)]; }
    else       { s = ei32[e];   d = ei32[EE+e]; }
  } else { s = e - EE; d = s; }
}

__global__ __launch_bounds__(256) void k_build(const int* __restrict__ ei32,
    unsigned* __restrict__ rowbits, unsigned* __restrict__ colbits, unsigned* __restrict__ cnt){
  int e = blockIdx.x*256 + threadIdx.x;
  if(e >= EP) return;
  int m = detect_mode(ei32), s, d;
  edge_sd(ei32, m, e, s, d);
  atomicOr(&rowbits[s*NWORDS + (d>>5)], 1u<<(d&31));
  atomicOr(&colbits[d*NWORDS + (s>>5)], 1u<<(s&31));
  atomicAdd(&cnt[d], 1u);
}

// block 0: exclusive scan of cnt -> rowptr; blocks 1..1024: v1 = popc rows (distinct out-deg)
__global__ __launch_bounds__(256) void k_scan_deg(const unsigned* __restrict__ cnt, unsigned* __restrict__ rowptr,
    const unsigned* __restrict__ rowbits, float* __restrict__ v1){
  int t = threadIdx.x;
  if(blockIdx.x == 0){
    __shared__ unsigned part[256];
    unsigned loc[16]; unsigned s = 0;
#pragma unroll
    for(int i=0;i<16;i++){ loc[i]=cnt[t*16+i]; s+=loc[i]; }
    part[t]=s; __syncthreads();
    for(int off=1;off<256;off<<=1){
      unsigned v = (t>=off)? part[t-off] : 0u;
      __syncthreads();
      part[t]+=v;
      __syncthreads();
    }
    unsigned run = (t==0)? 0u : part[t-1];
#pragma unroll
    for(int i=0;i<16;i++){ rowptr[t*16+i]=run; run+=loc[i]; }
    if(t==255) rowptr[NN]=run;
  } else {
    int node = (blockIdx.x-1)*4 + (t>>6);
    int lane = t & 63;
    unsigned w0 = rowbits[node*NWORDS + 2*lane];
    unsigned w1 = rowbits[node*NWORDS + 2*lane + 1];
    int c = __popc(w0) + __popc(w1);
    c = wredSumi(c);
    if(lane==0) v1[node] = (float)c;
  }
}

// blocks 0..527: CSR fill; blocks 528..1551: v2 = A @ v1
__global__ __launch_bounds__(256) void k_fill_mv(const int* __restrict__ ei32,
    const unsigned* __restrict__ rowptr, unsigned* __restrict__ fill, unsigned* __restrict__ csr_src,
    const unsigned* __restrict__ rowbits, const float* __restrict__ v1, float* __restrict__ v2){
  int t = threadIdx.x;
  if(blockIdx.x < 528){
    int e = blockIdx.x*256 + t;
    if(e >= EP) return;
    int m = detect_mode(ei32), s, d;
    edge_sd(ei32, m, e, s, d);
    unsigned pos = rowptr[d] + atomicAdd(&fill[d], 1u);
    csr_src[pos]=(unsigned)s;
  } else {
    int node = (blockIdx.x-528)*4 + (t>>6);
    int lane = t & 63;
    float sum = 0.f;
    unsigned w = rowbits[node*NWORDS + 2*lane]; int b0 = lane*64;
    while(w){ int b=__ffs(w)-1; sum += v1[b0+b]; w &= w-1; }
    w = rowbits[node*NWORDS + 2*lane + 1]; b0 = lane*64 + 32;
    while(w){ int b=__ffs(w)-1; sum += v1[b0+b]; w &= w-1; }
    sum = wredSumf(sum);
    if(lane==0) v2[node] = sum;
  }
}

// blocks 0..1023: v3 = A @ v2; 1024..2047: cvtA; 2048..3071: cvtB_all
__global__ __launch_bounds__(256) void k_mv2_cvt(const unsigned* __restrict__ rowbits,
    const float* __restrict__ v2, float* __restrict__ v3,
    const float* __restrict__ X, unsigned short* __restrict__ xh, unsigned short* __restrict__ xl,
    const float* __restrict__ W1f, const float* __restrict__ W2f, const float* __restrict__ Wrf,
    unsigned short* __restrict__ b1h, unsigned short* __restrict__ b1l,
    unsigned short* __restrict__ b2h, unsigned short* __restrict__ b2l){
  int t = threadIdx.x;
  int b = blockIdx.x;
  if(b < 1024){
    int node = b*4 + (t>>6);
    int lane = t & 63;
    float sum = 0.f;
    unsigned w = rowbits[node*NWORDS + 2*lane]; int b0 = lane*64;
    while(w){ int bb=__ffs(w)-1; sum += v2[b0+bb]; w &= w-1; }
    w = rowbits[node*NWORDS + 2*lane + 1]; b0 = lane*64 + 32;
    while(w){ int bb=__ffs(w)-1; sum += v2[b0+bb]; w &= w-1; }
    sum = wredSumf(sum);
    if(lane==0) v3[node] = sum;
  } else if(b < 2048){
    int e = (b-1024)*256 + t;
    int row = e >> 6;
    int c0 = (e & 63) * 8;
    const float4 v0 = *(const float4*)&X[(size_t)row*C1 + c0];
    const float4 v1q = *(const float4*)&X[(size_t)row*C1 + c0 + 4];
    float vv[8] = {v0.x,v0.y,v0.z,v0.w,v1q.x,v1q.y,v1q.z,v1q.w};
    unsigned short h[8], l[8];
#pragma unroll
    for(int j=0;j<8;j++) bfsplit(vv[j], h[j], l[j]);
    *(bf16x8*)&xh[(size_t)row*KP + c0] = *(bf16x8*)h;
    *(bf16x8*)&xl[(size_t)row*KP + c0] = *(bf16x8*)l;
  } else {
    int blk = b - 2048;
    const float* W; int N, n, nrow; unsigned short *bh, *bl;
    if(blk < 512){ W=W1f; N=512; n=blk;     nrow=n;     bh=b1h; bl=b1l; }
    else if(blk < 768){ W=W2f; N=256; n=blk-512; nrow=n;     bh=b2h; bl=b2l; }
    else { W=Wrf; N=256; n=blk-768; nrow=n+256; bh=b2h; bl=b2l; }
    int k = t*2;
    float a = W[(size_t)k*N + n];
    float bb = W[(size_t)(k+1)*N + n];
    unsigned short h0,l0,h1,l1;
    bfsplit(a,h0,l0); bfsplit(bb,h1,l1);
    unsigned short hp[2]={h0,h1}, lp[2]={l0,l1};
    *(unsigned int*)&bh[(size_t)nrow*KP + k] = *(unsigned int*)hp;
    *(unsigned int*)&bl[(size_t)nrow*KP + k] = *(unsigned int*)lp;
  }
}

// per-dst: bit-plane counters g[k]=A^2[k,d] in REGISTERS; A^3 via popc; mwc in CSR order
__global__ __launch_bounds__(64) void k_motif(const unsigned* __restrict__ rowbits, const unsigned* __restrict__ colbits,
    const unsigned* __restrict__ rowptr, const unsigned* __restrict__ csr_src,
    const float* __restrict__ v3, float* __restrict__ mwc){
  int d = blockIdx.x;
  int lane = threadIdx.x;
  __shared__ unsigned short nbr[1024];
  __shared__ int cntL;
  if(lane==0) cntL=0;
  __syncthreads();
  {
    unsigned w = colbits[d*NWORDS + 2*lane]; int b0 = lane*64;
    while(w){ int b=__ffs(w)-1; int pos=atomicAdd(&cntL,1); nbr[pos]=(unsigned short)(b0+b); w&=w-1; }
    w = colbits[d*NWORDS + 2*lane + 1]; b0 = lane*64 + 32;
    while(w){ int b=__ffs(w)-1; int pos=atomicAdd(&cntL,1); nbr[pos]=(unsigned short)(b0+b); w&=w-1; }
  }
  __syncthreads();
  int m = cntL;
  unsigned gp[8][2];
#pragma unroll
  for(int p=0;p<8;p++){ gp[p][0]=0u; gp[p][1]=0u; }
  for(int t0=0;t0<m;t0+=4){
    unsigned xa[4], xb[4];
#pragma unroll
    for(int j=0;j<4;j++){
      int tt=t0+j;
      if(tt<m){ int l = nbr[tt]; xa[j]=colbits[l*NWORDS+2*lane]; xb[j]=colbits[l*NWORDS+2*lane+1]; }
      else    { xa[j]=0u; xb[j]=0u; }
    }
#pragma unroll
    for(int j=0;j<4;j++){
      unsigned c = xa[j];
#pragma unroll
      for(int p=0;p<8;p++){ unsigned cy = gp[p][0] & c; gp[p][0] ^= c; c = cy; }
      c = xb[j];
#pragma unroll
      for(int p=0;p<8;p++){ unsigned cy = gp[p][1] & c; gp[p][1] ^= c; c = cy; }
    }
  }
  unsigned base = rowptr[d], deg = rowptr[d+1]-base;
  for(unsigned i0=0;i0<deg;i0+=4){
    unsigned sidx[4], ra[4], rb[4];
#pragma unroll
    for(int j=0;j<4;j++){
      unsigned ii = (i0+j < deg) ? (i0+j) : (deg-1);
      sidx[j] = csr_src[base+ii];
    }
#pragma unroll
    for(int j=0;j<4;j++){ ra[j]=rowbits[sidx[j]*NWORDS+2*lane]; rb[j]=rowbits[sidx[j]*NWORDS+2*lane+1]; }
    int sum[4];
#pragma unroll
    for(int j=0;j<4;j++){
      int s=0;
#pragma unroll
      for(int p=0;p<8;p++)
        s += (__popc(ra[j]&gp[p][0]) + __popc(rb[j]&gp[p][1])) << p;
      sum[j]=s;
    }
    int pk0 = sum[0] | (sum[1]<<16);
    int pk1 = sum[2] | (sum[3]<<16);
    pk0 = wredSumi(pk0); pk1 = wredSumi(pk1);
    if(lane==0){
      int ss[4] = { pk0 & 0xFFFF, (pk0>>16)&0xFFFF, pk1 & 0xFFFF, (pk1>>16)&0xFFFF };
#pragma unroll
      for(int j=0;j<4;j++){
        unsigned idx = i0+j;
        if(idx<deg)
          mwc[base+idx] = (float)ss[j] / fmaxf(v3[csr_src[base+idx]], 1.0f);
      }
    }
  }
}

// ---- split-bf16 MFMA GEMM + fused attention-dot epilogue ----
// amode=1: 8 heads over 512 cols (oS/oD stride 8); amode=2: 1 head over cols<256 (stride 1)
__global__ __launch_bounds__(256) void k_gemm_mfma(
    const unsigned short* __restrict__ Ah, const unsigned short* __restrict__ Al,
    const unsigned short* __restrict__ Bh, const unsigned short* __restrict__ Bl,
    float* __restrict__ C, int M, int N,
    const float* __restrict__ aS, const float* __restrict__ aD,
    float* __restrict__ oS, float* __restrict__ oD, int amode){
  __shared__ unsigned short Ahs[64][72], Als[64][72], Bhs[64][72], Bls[64][72];
  int bm = blockIdx.y*64, bn = blockIdx.x*64;
  int t = threadIdx.x, lane = t&63, w = t>>6;
  int wm = (w>>1)*32, wn = (w&1)*32;
  f32x4 acc[2][2];
#pragma unroll
  for(int i=0;i<2;i++)
#pragma unroll
    for(int j=0;j<2;j++) acc[i][j] = (f32x4){0.f,0.f,0.f,0.f};
  int sm = t>>2, sk = (t&3)*16;
  const unsigned short* pAh = &Ah[(size_t)(bm+sm)*KP + sk];
  const unsigned short* pAl = &Al[(size_t)(bm+sm)*KP + sk];
  const unsigned short* pBh = &Bh[(size_t)(bn+sm)*KP + sk];
  const unsigned short* pBl = &Bl[(size_t)(bn+sm)*KP + sk];
  int fr = lane&15, kg = lane>>4;
  bf16x8 rah0 = *(const bf16x8*)(pAh), rah1 = *(const bf16x8*)(pAh+8);
  bf16x8 ral0 = *(const bf16x8*)(pAl), ral1 = *(const bf16x8*)(pAl+8);
  bf16x8 rbh0 = *(const bf16x8*)(pBh), rbh1 = *(const bf16x8*)(pBh+8);
  bf16x8 rbl0 = *(const bf16x8*)(pBl), rbl1 = *(const bf16x8*)(pBl+8);
  *(bf16x8*)&Ahs[sm][sk] = rah0; *(bf16x8*)&Ahs[sm][sk+8] = rah1;
  *(bf16x8*)&Als[sm][sk] = ral0; *(bf16x8*)&Als[sm][sk+8] = ral1;
  *(bf16x8*)&Bhs[sm][sk] = rbh0; *(bf16x8*)&Bhs[sm][sk+8] = rbh1;
  *(bf16x8*)&Bls[sm][sk] = rbl0; *(bf16x8*)&Bls[sm][sk+8] = rbl1;
  __syncthreads();
  for(int k0=0;k0<C1;k0+=64){
    int kn = k0+64;
    if(kn<C1){
      rah0 = *(const bf16x8*)(pAh+kn); rah1 = *(const bf16x8*)(pAh+kn+8);
      ral0 = *(const bf16x8*)(pAl+kn); ral1 = *(const bf16x8*)(pAl+kn+8);
      rbh0 = *(const bf16x8*)(pBh+kn); rbh1 = *(const bf16x8*)(pBh+kn+8);
      rbl0 = *(const bf16x8*)(pBl+kn); rbl1 = *(const bf16x8*)(pBl+kn+8);
    }
#pragma unroll
    for(int ks=0;ks<64;ks+=32){
      bf16x8 fah[2], fal[2], fbh[2], fbl[2];
#pragma unroll
      for(int i=0;i<2;i++){
        fah[i] = *(bf16x8*)&Ahs[wm + i*16 + fr][ks + kg*8];
        fal[i] = *(bf16x8*)&Als[wm + i*16 + fr][ks + kg*8];
        fbh[i] = *(bf16x8*)&Bhs[wn + i*16 + fr][ks + kg*8];
        fbl[i] = *(bf16x8*)&Bls[wn + i*16 + fr][ks + kg*8];
      }
#pragma unroll
      for(int i=0;i<2;i++)
#pragma unroll
        for(int j=0;j<2;j++){
          acc[i][j] = __builtin_amdgcn_mfma_f32_16x16x32_bf16(fah[i], fbh[j], acc[i][j], 0,0,0);
          acc[i][j] = __builtin_amdgcn_mfma_f32_16x16x32_bf16(fah[i], fbl[j], acc[i][j], 0,0,0);
          acc[i][j] = __builtin_amdgcn_mfma_f32_16x16x32_bf16(fal[i], fbh[j], acc[i][j], 0,0,0);
        }
    }
    __syncthreads();
    if(kn<C1){
      *(bf16x8*)&Ahs[sm][sk] = rah0; *(bf16x8*)&Ahs[sm][sk+8] = rah1;
      *(bf16x8*)&Als[sm][sk] = ral0; *(bf16x8*)&Als[sm][sk+8] = ral1;
      *(bf16x8*)&Bhs[sm][sk] = rbh0; *(bf16x8*)&Bhs[sm][sk+8] = rbh1;
      *(bf16x8*)&Bls[sm][sk] = rbl0; *(bf16x8*)&Bls[sm][sk+8] = rbl1;
    }
    __syncthreads();
  }
#pragma unroll
  for(int i=0;i<2;i++)
#pragma unroll
    for(int j=0;j<2;j++){
      int gr = bm + wm + i*16 + kg*4;
      int gc = bn + wn + j*16 + fr;
#pragma unroll
      for(int e=0;e<4;e++)
        C[(size_t)(gr+e)*N + gc] = acc[i][j][e];
    }
  // fused attention dots: per-row partial over this block's 64 cols (single head per block)
  bool do_attn = (amode==1) || (bn < 256);
  if(do_attn){
    float p1[2][4], p2[2][4];
#pragma unroll
    for(int i=0;i<2;i++)
#pragma unroll
      for(int e=0;e<4;e++){ p1[i][e]=0.f; p2[i][e]=0.f; }
#pragma unroll
    for(int j=0;j<2;j++){
      int col = bn + wn + j*16 + fr;
      float a1c = aS[col], a2c = aD[col];
#pragma unroll
      for(int i=0;i<2;i++)
#pragma unroll
        for(int e=0;e<4;e++){ p1[i][e] += acc[i][j][e]*a1c; p2[i][e] += acc[i][j][e]*a2c; }
    }
#pragma unroll
    for(int o=1;o<16;o<<=1){
#pragma unroll
      for(int i=0;i<2;i++)
#pragma unroll
        for(int e=0;e<4;e++){ p1[i][e]+=__shfl_xor(p1[i][e],o); p2[i][e]+=__shfl_xor(p2[i][e],o); }
    }
    if(fr==0){
      int head = (amode==1)? (bn>>6) : 0;
      int hs = (amode==1)? H1 : 1;
#pragma unroll
      for(int i=0;i<2;i++)
#pragma unroll
        for(int e=0;e<4;e++){
          int row = bm + wm + i*16 + kg*4 + e;
          atomicAdd(&oS[row*hs + head], p1[i][e]);
          atomicAdd(&oD[row*hs + head], p2[i][e]);
        }
    }
  }
}

// layer-1: flash-style single-sweep dual segment-softmax + aggregation + bias + ELU
__global__ __launch_bounds__(128) void k_layer1(const unsigned* __restrict__ rowptr, const unsigned* __restrict__ csr_src,
    const float* __restrict__ mwc, const float* __restrict__ asrc, const float* __restrict__ adst,
    const float* __restrict__ hpre, const float* __restrict__ b1,
    unsigned short* __restrict__ h1h, unsigned short* __restrict__ h1l){
  int n = blockIdx.x;
  int tid = threadIdx.x, lane = tid&63, wv = tid>>6;
  unsigned base = rowptr[n], deg = rowptr[n+1]-base;
  __shared__ float a1s[128][9];
  __shared__ float a2s[128][9];
  __shared__ unsigned ssrc[128];
  __shared__ float red1[2][8], red2[2][8];
  __shared__ float snm1[8], snm2[8], sscl1[8], sscl2[8];
  __shared__ float sS1[8], sS2[8], sM1[8], sM2[8];
  __shared__ float adsts[8];
  if(tid<8){ adsts[tid]=adst[n*H1+tid]; sM1[tid]=-3.0e38f; sM2[tid]=-3.0e38f; sS1[tid]=0.f; sS2[tid]=0.f; }
  __syncthreads();
  int h = tid>>4;
  float4 acc1={0.f,0.f,0.f,0.f}, acc2={0.f,0.f,0.f,0.f};
  for(unsigned c0=0;c0<deg;c0+=128){
    int csz = (int)min(128u, deg-c0);
    bool act = (tid < csz);
    float el[8], em[8];
    if(act){
      unsigned s = csr_src[base+c0+tid];
      ssrc[tid]=s;
      float mwv = mwc[base+c0+tid];
      const float4 a0v = *(const float4*)&asrc[s*H1];
      const float4 a1v = *(const float4*)&asrc[s*H1+4];
      float as8[8]={a0v.x,a0v.y,a0v.z,a0v.w,a1v.x,a1v.y,a1v.z,a1v.w};
#pragma unroll
      for(int hh=0;hh<8;hh++){
        float ev = as8[hh]+adsts[hh];
        el[hh] = ev>=0.f? ev : 0.2f*ev;
        float evm = ev*mwv;
        em[hh] = evm>=0.f? evm : 0.2f*evm;
      }
    } else {
#pragma unroll
      for(int hh=0;hh<8;hh++){ el[hh]=-3.0e38f; em[hh]=-3.0e38f; }
    }
    float mx1[8], mx2[8];
#pragma unroll
    for(int hh=0;hh<8;hh++){ mx1[hh]=wredMaxf(el[hh]); mx2[hh]=wredMaxf(em[hh]); }
    if(lane==0){
#pragma unroll
      for(int hh=0;hh<8;hh++){ red1[wv][hh]=mx1[hh]; red2[wv][hh]=mx2[hh]; }
    }
    __syncthreads();
    if(tid<8){
      float cm1 = fmaxf(red1[0][tid], red1[1][tid]);
      float cm2 = fmaxf(red2[0][tid], red2[1][tid]);
      float nm1 = fmaxf(sM1[tid], cm1), nm2 = fmaxf(sM2[tid], cm2);
      sscl1[tid] = expf(sM1[tid]-nm1); sscl2[tid] = expf(sM2[tid]-nm2);
      snm1[tid]=nm1; snm2[tid]=nm2;
      sM1[tid]=nm1;  sM2[tid]=nm2;
    }
    __syncthreads();
    float s1l[8], s2l[8];
#pragma unroll
    for(int hh=0;hh<8;hh++){
      float a1v = act? expf(el[hh]-snm1[hh]) : 0.f;
      float a2v = act? expf(em[hh]-snm2[hh]) : 0.f;
      if(act){ a1s[tid][hh]=a1v; a2s[tid][hh]=a2v; }
      s1l[hh]=a1v; s2l[hh]=a2v;
    }
#pragma unroll
    for(int hh=0;hh<8;hh++){ s1l[hh]=wredSumf(s1l[hh]); s2l[hh]=wredSumf(s2l[hh]); }
    if(lane==0){
#pragma unroll
      for(int hh=0;hh<8;hh++){ red1[wv][hh]=s1l[hh]; red2[wv][hh]=s2l[hh]; }
    }
    __syncthreads();
    if(tid<8){
      sS1[tid] = sS1[tid]*sscl1[tid] + red1[0][tid]+red1[1][tid];
      sS2[tid] = sS2[tid]*sscl2[tid] + red2[0][tid]+red2[1][tid];
    }
    {
      float sc1 = sscl1[h], sc2 = sscl2[h];
      acc1.x*=sc1; acc1.y*=sc1; acc1.z*=sc1; acc1.w*=sc1;
      acc2.x*=sc2; acc2.y*=sc2; acc2.z*=sc2; acc2.w*=sc2;
    }
    for(int i0=0;i0<csz;i0+=8){
      int jn = min(8, csz-i0);
      unsigned sj[8]; float a1j[8], a2j[8];
#pragma unroll
      for(int j=0;j<8;j++){
        int ii = (j<jn)? i0+j : i0;
        sj[j]=ssrc[ii]; a1j[j]=a1s[ii][h]; a2j[j]=a2s[ii][h];
      }
      float4 hv[8];
#pragma unroll
      for(int j=0;j<8;j++) hv[j] = *(const float4*)&hpre[(size_t)sj[j]*C1 + tid*4];
#pragma unroll
      for(int j=0;j<8;j++){
        float w1 = (j<jn)? a1j[j] : 0.f;
        float w2 = (j<jn)? a2j[j] : 0.f;
        acc1.x += w1*hv[j].x; acc1.y += w1*hv[j].y; acc1.z += w1*hv[j].z; acc1.w += w1*hv[j].w;
        acc2.x += w2*hv[j].x; acc2.y += w2*hv[j].y; acc2.z += w2*hv[j].z; acc2.w += w2*hv[j].w;
      }
    }
    __syncthreads();
  }
  float r1 = 0.5f/(sS1[h]+1e-16f), r2 = 0.5f/(sS2[h]+1e-16f);
  int cc = tid*4;
  const float4 bv = *(const float4*)&b1[cc];
  float o[4];
  float vx = acc1.x*r1 + acc2.x*r2 + bv.x; o[0] = vx>0.f? vx : expm1f(vx);
  float vy = acc1.y*r1 + acc2.y*r2 + bv.y; o[1] = vy>0.f? vy : expm1f(vy);
  float vz = acc1.z*r1 + acc2.z*r2 + bv.z; o[2] = vz>0.f? vz : expm1f(vz);
  float vw = acc1.w*r1 + acc2.w*r2 + bv.w; o[3] = vw>0.f? vw : expm1f(vw);
  unsigned short hh4[4], ll4[4];
#pragma unroll
  for(int j=0;j<4;j++) bfsplit(o[j], hh4[j], ll4[j]);
  *(ushort4*)&h1h[(size_t)n*KP + cc] = *(ushort4*)hh4;
  *(ushort4*)&h1l[(size_t)n*KP + cc] = *(ushort4*)ll4;
}

// layer-2: flash-style single-sweep + residual + bias -> d_out; h2/res row stride 512
__global__ __launch_bounds__(64) void k_layer2(const unsigned* __restrict__ rowptr, const unsigned* __restrict__ csr_src,
    const float* __restrict__ mwc, const float* __restrict__ asrc, const float* __restrict__ adst,
    const float* __restrict__ h2, const float* __restrict__ res,
    const float* __restrict__ b2, float* __restrict__ out){
  int n = blockIdx.x; int lane = threadIdx.x;
  unsigned base = rowptr[n], deg = rowptr[n+1]-base;
  __shared__ float a1s[64], a2s[64];
  __shared__ unsigned ssrc[64];
  float ad = adst[n];
  float M1=-3.0e38f, M2=-3.0e38f, S1=0.f, S2=0.f;
  float4 acc1={0.f,0.f,0.f,0.f}, acc2={0.f,0.f,0.f,0.f};
  for(unsigned c0=0;c0<deg;c0+=64){
    int csz = (int)min(64u, deg-c0);
    bool act = (lane < csz);
    float el=-3.0e38f, em=-3.0e38f;
    if(act){
      unsigned s = csr_src[base+c0+lane];
      ssrc[lane]=s;
      float mwv = mwc[base+c0+lane];
      float ev = asrc[s] + ad;
      el = ev>=0.f? ev : 0.2f*ev;
      float evm = ev*mwv;
      em = evm>=0.f? evm : 0.2f*evm;
    }
    float nm1 = fmaxf(M1, wredMaxf(el));
    float nm2 = fmaxf(M2, wredMaxf(em));
    float sc1 = expf(M1-nm1), sc2 = expf(M2-nm2);
    M1=nm1; M2=nm2;
    float a1 = act? expf(el-nm1) : 0.f;
    float a2 = act? expf(em-nm2) : 0.f;
    if(act){ a1s[lane]=a1; a2s[lane]=a2; }
    S1 = S1*sc1 + wredSumf(a1);
    S2 = S2*sc2 + wredSumf(a2);
    acc1.x*=sc1; acc1.y*=sc1; acc1.z*=sc1; acc1.w*=sc1;
    acc2.x*=sc2; acc2.y*=sc2; acc2.z*=sc2; acc2.w*=sc2;
    __syncthreads();
    for(int i0=0;i0<csz;i0+=8){
      int jn = min(8, csz-i0);
      unsigned sj[8]; float a1j[8], a2j[8];
#pragma unroll
      for(int j=0;j<8;j++){
        int ii = (j<jn)? i0+j : i0;
        sj[j]=ssrc[ii]; a1j[j]=a1s[ii]; a2j[j]=a2s[ii];
      }
      float4 hv[8];
#pragma unroll
      for(int j=0;j<8;j++) hv[j] = *(const float4*)&h2[(size_t)sj[j]*512 + lane*4];
#pragma unroll
      for(int j=0;j<8;j++){
        float w1 = (j<jn)? a1j[j] : 0.f;
        float w2 = (j<jn)? a2j[j] : 0.f;
        acc1.x += w1*hv[j].x; acc1.y += w1*hv[j].y; acc1.z += w1*hv[j].z; acc1.w += w1*hv[j].w;
        acc2.x += w2*hv[j].x; acc2.y += w2*hv[j].y; acc2.z += w2*hv[j].z; acc2.w += w2*hv[j].w;
      }
    }
    __syncthreads();
  }
  float r1 = 0.5f/(S1+1e-16f), r2 = 0.5f/(S2+1e-16f);
  int cc = lane*4;
  const float4 rv = *(const float4*)&res[(size_t)n*512 + cc];
  const float4 bv = *(const float4*)&b2[cc];
  float4 o = {acc1.x*r1 + acc2.x*r2 + rv.x + bv.x,
              acc1.y*r1 + acc2.y*r2 + rv.y + bv.y,
              acc1.z*r1 + acc2.z*r2 + rv.z + bv.z,
              acc1.w*r1 + acc2.w*r2 + rv.w + bv.w};
  *(float4*)&out[(size_t)n*C2 + cc] = o;
}

extern "C" void kernel_launch(void* const* d_in, const int* in_sizes, int n_in,
                              void* d_out, int out_size, void* d_ws, size_t ws_size,
                              hipStream_t stream) {
  const float* x    = (const float*)d_in[0];
  const int*   ei32 = (const int*)d_in[1];
  const float* W1   = (const float*)d_in[2];
  const float* as1  = (const float*)d_in[3];
  const float* ad1  = (const float*)d_in[4];
  const float* b1   = (const float*)d_in[5];
  const float* W2   = (const float*)d_in[6];
  const float* as2  = (const float*)d_in[7];
  const float* ad2  = (const float*)d_in[8];
  const float* b2   = (const float*)d_in[9];
  const float* resW2= (const float*)d_in[10];
  float* out = (float*)d_out;

  char* p = (char*)d_ws;
  auto alloc = [&](size_t b){ void* r=(void*)p; p += (b + 255) & ~(size_t)255; return r; };
  // zero-init region: rowbits, colbits, cnt, fill, asrc1, adst1, asrc2, adst2 — contiguous
  unsigned* rowbits = (unsigned*)alloc((size_t)NN*NWORDS*4);   // 2MB
  unsigned* colbits = (unsigned*)alloc((size_t)NN*NWORDS*4);   // 2MB
  unsigned* cnt     = (unsigned*)alloc(NN*4);
  unsigned* fill    = (unsigned*)alloc(NN*4);
  float* asrc1= (float*)alloc(NN*H1*4);
  float* adst1= (float*)alloc(NN*H1*4);
  float* asrc2= (float*)alloc(NN*4);
  float* adst2= (float*)alloc(NN*4);
  size_t zbytes = (size_t)(p - (char*)rowbits);
  unsigned* rowptr  = (unsigned*)alloc((NN+4)*4);
  float* v1 = (float*)alloc(NN*4);
  float* v2 = (float*)alloc(NN*4);
  float* v3 = (float*)alloc(NN*4);
  unsigned* csr_src = (unsigned*)alloc((size_t)EP*4);
  float* mwc  = (float*)alloc((size_t)EP*4);
  unsigned short* xsh = (unsigned short*)alloc((size_t)NN*KP*2);
  unsigned short* xsl = (unsigned short*)alloc((size_t)NN*KP*2);
  unsigned short* bt1h= (unsigned short*)alloc((size_t)C1*KP*2);
  unsigned short* bt1l= (unsigned short*)alloc((size_t)C1*KP*2);
  unsigned short* bt2h= (unsigned short*)alloc((size_t)C1*KP*2);  // stacked W2|resW2
  unsigned short* bt2l= (unsigned short*)alloc((size_t)C1*KP*2);
  float* hpre = (float*)alloc((size_t)NN*C1*4);
  unsigned short* h1h = (unsigned short*)alloc((size_t)NN*KP*2);
  unsigned short* h1l = (unsigned short*)alloc((size_t)NN*KP*2);
  float* c23  = (float*)alloc((size_t)NN*512*4);  // cols 0-255 = h2, 256-511 = res
  float* h2  = c23;
  float* res = c23 + 256;

  hipMemsetAsync(rowbits, 0, zbytes, stream);

  k_build<<<(EP+255)/256,256,0,stream>>>(ei32, rowbits, colbits, cnt);
  k_scan_deg<<<1+NN/4,256,0,stream>>>(cnt, rowptr, rowbits, v1);
  k_fill_mv<<<528+NN/4,256,0,stream>>>(ei32, rowptr, fill, csr_src, rowbits, v1, v2);
  k_mv2_cvt<<<3072,256,0,stream>>>(rowbits, v2, v3, x, xsh, xsl, W1, W2, resW2, bt1h, bt1l, bt2h, bt2l);
  k_motif<<<NN,64,0,stream>>>(rowbits, colbits, rowptr, csr_src, v3, mwc);

  k_gemm_mfma<<<dim3(C1/64, NN/64),256,0,stream>>>(xsh, xsl, bt1h, bt1l, hpre, NN, C1,
                                                   as1, ad1, asrc1, adst1, 1);
  k_layer1<<<NN,128,0,stream>>>(rowptr, csr_src, mwc, asrc1, adst1, hpre, b1, h1h, h1l);

  k_gemm_mfma<<<dim3(512/64, NN/64),256,0,stream>>>(h1h, h1l, bt2h, bt2l, c23, NN, 512,
                                                    as2, ad2, asrc2, adst2, 2);
  k_layer2<<<NN,64,0,stream>>>(rowptr, csr_src, mwc, asrc2, adst2, h2, res, b2, out);
}